// Round 4
// baseline (252.322 us; speedup 1.0000x reference)
//
#include <hip/hip_runtime.h>
#include <math.h>

// ---------------------------------------------------------------------------
// IrrepsToHessian, round 12.
//
// Budget model (fits R8/R9/R11 within noise): 43.5us ws-poison fill (always
// runs) + ~14.5us harness floor + kernels. R9 kernels = 46.5 (fused2, DS-
// issue bound: ~1250 DS instr/wave x 16 waves/CU x ~5.8cyc ~ 47us) + 8 (sym).
//
// R10 failed via RUNTIME readlane indices (waterfall -> scratch, 170MB TCC).
// R11 failed via VMEM-latency-chained global Mq loads (VALUBusy 9%).
//
// R12 = R9 structure with DS work removed by static on-chip means only:
//  1. Phase A: transposed x1/tpw -> 8x ds_read_b128 per c (bit-identical).
//  2. Phase B: Mq[c][a] stays in REGISTERS (27 VGPR: mq0/mq1/mq2).
//     cart reads via FULLY-UNROLLED static-index v_readlane (SGPR operand
//     FMAs; no LDS, no global, no waterfall). sMq deleted.
//  3. cart x: b128 from pad-148 row-major sX2 (37 f4/row -> conflict-free).
//  ws UNUSED. LDS ~50.6KB -> 3 blocks/CU. FP order identical to R9.
// ---------------------------------------------------------------------------

#define NPATH 15

// ======================= compile-time Wigner machinery =====================
constexpr double cfact(int n){ double r = 1.0; for (int i = 2; i <= n; ++i) r *= (double)i; return r; }
constexpr double csqrt(double x){
  if (x <= 0.0) return 0.0;
  double g = x < 1.0 ? 1.0 : x;
  for (int i = 0; i < 64; ++i) g = 0.5*(g + x/g);
  return g;
}

constexpr double ccg(int j1,int m1,int j2,int m2,int j3,int m3){
  if (m3 != m1 + m2) return 0.0;
  int vmin = -j1 + j2 + m3;
  if (-j1 + m1 > vmin) vmin = -j1 + m1;
  if (0 > vmin) vmin = 0;
  int vmax = j2 + j3 + m1;
  if (j3 - j1 + j2 < vmax) vmax = j3 - j1 + j2;
  if (j3 + m3 < vmax) vmax = j3 + m3;
  double C = csqrt((2.0*j3+1.0)*cfact(j3+j1-j2)*cfact(j3-j1+j2)*cfact(j1+j2-j3)
                   *cfact(j3+m3)*cfact(j3-m3)
                   /(cfact(j1+j2+j3+1)*cfact(j1-m1)*cfact(j1+m1)*cfact(j2-m2)*cfact(j2+m2)));
  double S = 0.0;
  for (int v = vmin; v <= vmax; ++v){
    double term = cfact(j2+j3+m1-v)*cfact(j1-m1+v)
                /(cfact(v)*cfact(j3-j1+j2-v)*cfact(j3+m3-v)*cfact(v+j1-j2-m3));
    S += ((v + j2 + m2) & 1) ? -term : term;
  }
  return C * S;
}

struct QM { double re[5][5]; double im[5][5]; };
constexpr QM cbuild_q(int l){
  QM q{};
  double s = 1.0 / csqrt(2.0);
  for (int m = -l; m < 0; ++m){
    q.re[l+m][l-m] = s;
    q.im[l+m][l+m] = -s;
  }
  q.re[l][l] = 1.0;
  for (int m = 1; m <= l; ++m){
    double sg = (m & 1) ? -1.0 : 1.0;
    q.re[l+m][l+m] = sg * s;
    q.im[l+m][l-m] = sg * s;
  }
  if (l == 1){           // * (-i): (a+bi) -> (b, -a)
    for (int r = 0; r < 5; ++r)
      for (int c = 0; c < 5; ++c){
        double a = q.re[r][c], b = q.im[r][c];
        q.re[r][c] = b; q.im[r][c] = -a;
      }
  } else if (l == 2){    // * (-1)
    for (int r = 0; r < 5; ++r)
      for (int c = 0; c < 5; ++c){ q.re[r][c] = -q.re[r][c]; q.im[r][c] = -q.im[r][c]; }
  }
  return q;
}

struct CRP { double v[125]; };   // normalized real w3j, [(i*d2+j)*d3+m]
constexpr CRP make_cr(int l1, int l2, int l3){
  QM q1 = cbuild_q(l1), q2 = cbuild_q(l2), q3 = cbuild_q(l3);
  const int d1 = 2*l1+1, d2 = 2*l2+1, d3 = 2*l3+1;
  double CG[125] = {};
  for (int i = 0; i < d1; ++i)
    for (int k = 0; k < d2; ++k)
      for (int m = 0; m < d3; ++m)
        CG[(i*5 + k)*5 + m] = ccg(l1, i-l1, l2, k-l2, l3, m-l3);
  CRP o{};
  for (int j = 0; j < d1; ++j)
    for (int l = 0; l < d2; ++l)
      for (int n = 0; n < d3; ++n){
        double acc = 0.0;
        for (int i = 0; i < d1; ++i)
          for (int k = 0; k < d2; ++k)
            for (int m = 0; m < d3; ++m){
              double c = CG[(i*5 + k)*5 + m];
              if (c == 0.0) continue;
              double are = q1.re[i][j], aim = q1.im[i][j];
              double bre = q2.re[k][l], bim = q2.im[k][l];
              double tre = are*bre - aim*bim;
              double tim = are*bim + aim*bre;
              double cre = q3.re[m][n], cim = q3.im[m][n];
              acc += (tre*cre + tim*cim) * c;   // Re( q1 q2 conj(q3) CG )
            }
        o.v[(j*d2 + l)*d3 + n] = acc;
      }
  double s2 = 0.0;
  for (int e = 0; e < d1*d2*d3; ++e) s2 += o.v[e]*o.v[e];
  double inv = 1.0 / csqrt(s2);
  for (int e = 0; e < d1*d2*d3; ++e) o.v[e] *= inv;
  return o;
}

constexpr CRP CR0  = make_cr(0,0,0);
constexpr CRP CR1  = make_cr(1,1,0);
constexpr CRP CR2  = make_cr(2,2,0);
constexpr CRP CR3  = make_cr(0,1,1);
constexpr CRP CR4  = make_cr(1,0,1);
constexpr CRP CR5  = make_cr(1,1,1);
constexpr CRP CR6  = make_cr(1,2,1);
constexpr CRP CR7  = make_cr(2,1,1);
constexpr CRP CR8  = make_cr(2,2,1);
constexpr CRP CR9  = make_cr(0,2,2);
constexpr CRP CR10 = make_cr(2,0,2);
constexpr CRP CR11 = make_cr(1,1,2);
constexpr CRP CR12 = make_cr(1,2,2);
constexpr CRP CR13 = make_cr(2,1,2);
constexpr CRP CR14 = make_cr(2,2,2);

struct QCT { double v[81]; };    // QCART[lm][i*3+j]
constexpr QCT make_qc(){
  QCT q{};
  for (int lm = 0; lm < 9; ++lm){
    int l = (lm == 0) ? 0 : ((lm < 4) ? 1 : 2);
    int m = lm - l*l;
    const CRP& cr = (l == 0) ? CR1 : ((l == 1) ? CR5 : CR11);  // paths (1,1,l)
    double sc = csqrt(2.0*l + 1.0);
    for (int r = 0; r < 9; ++r)
      q.v[lm*9 + r] = cr.v[r*(2*l+1) + m] * sc;
  }
  return q;
}
constexpr QCT QCt = make_qc();

// wq layout: 189 rows, split b8 (a<8) + b1 (a==8)
struct WQT { float b8[189*8]; float b1[189]; };
constexpr WQT make_wq(){
  WQT t{};
  const CRP* crs[NPATH] = {&CR0,&CR1,&CR2,&CR3,&CR4,&CR5,&CR6,&CR7,&CR8,&CR9,
                           &CR10,&CR11,&CR12,&CR13,&CR14};
  const int L1[NPATH]   = {0,1,2,0,1,1,1,2,2,0,2,1,1,2,2};
  const int L2[NPATH]   = {0,1,2,1,0,1,2,1,2,2,0,1,2,1,2};
  const int LO[NPATH]   = {0,0,0,1,1,1,1,1,1,2,2,2,2,2,2};
  const int PROW[NPATH] = {0,1,10,35,38,41,50,65,80,105,110,115,124,139,164};
  const double AL[3] = { csqrt(1.0/768.0), csqrt(3.0/1536.0), csqrt(5.0/1536.0) };
  for (int p = 0; p < NPATH; ++p){
    const int d1 = 2*L1[p]+1, d2 = 2*L2[p]+1, d3 = 2*LO[p]+1, lo = LO[p];
    for (int i = 0; i < d1; ++i)
      for (int j = 0; j < d2; ++j)
        for (int a = 0; a < 9; ++a){
          double acc = 0.0;
          for (int m = 0; m < d3; ++m)
            acc += crs[p]->v[(i*d2 + j)*d3 + m] * QCt.v[(lo*lo + m)*9 + a];
          double val = AL[lo] * acc;
          int row = PROW[p] + i*d2 + j;
          if (a < 8) t.b8[row*8 + a] = (float)val;
          else       t.b1[row]       = (float)val;
        }
  }
  return t;
}
__constant__ WQT cWQ = make_wq();

// ======================= runtime tables ====================================
__constant__ int cP_L1[NPATH]   = {0,1,2,0,1,1,1,2,2,0,2,1,1,2,2};
__constant__ int cC2P[51] = {0, 1,1,1, 2,2,2,2,2, 3, 4,4,4, 5,5,5, 6,6,6,
                             7,7,7,7,7, 8,8,8,8,8, 9, 10,10,10,10,10,
                             11,11,11, 12,12,12, 13,13,13,13,13, 14,14,14,14,14};
__constant__ int cC2I[51] = {0, 0,1,2, 0,1,2,3,4, 0, 0,1,2, 0,1,2, 0,1,2,
                             0,1,2,3,4, 0,1,2,3,4, 0, 0,1,2,3,4,
                             0,1,2, 0,1,2, 0,1,2,3,4, 0,1,2,3,4};

// ACCP: one path's contribution to acc[9] (reads pT, sB8, sB1, v, j, D2)
#define ACCP(TOFF_, PROW_, D1_)                                              \
  { _Pragma("unroll")                                                        \
    for (int i = 0; i < (D1_); ++i){                                         \
      float tv = pT[((TOFF_) + i) * 16 + v];                                 \
      int row = (PROW_) + i * D2 + j;                                        \
      const float4 m0 = *(const float4*)&sB8[row * 8];                       \
      const float4 m1 = *(const float4*)&sB8[row * 8 + 4];                   \
      const float  m8 = sB1[row];                                            \
      acc[0] += tv*m0.x; acc[1] += tv*m0.y; acc[2] += tv*m0.z;               \
      acc[3] += tv*m0.w; acc[4] += tv*m1.x; acc[5] += tv*m1.y;               \
      acc[6] += tv*m1.z; acc[7] += tv*m1.w; acc[8] += tv*m8;                 \
    } }

// Mq for one c (R9-identical math/order)
__device__ __forceinline__ void mqc(int c, const float* pT, const float* sB8,
                                    const float* sB1, float (&acc)[9]){
  #pragma unroll
  for (int a = 0; a < 9; ++a) acc[a] = 0.f;
  if (c < 16){                    // l2 = 0 : paths 0,4,10
    const int v = c, j = 0;
    const int D2 = 1;
    ACCP(0,  0,   1)
    ACCP(10, 38,  3)
    ACCP(30, 110, 5)
  } else if (c < 64){             // l2 = 1 : paths 1,3,5,7,11,13
    const int v = (c - 16) / 3, j = (c - 16) % 3;
    const int D2 = 3;
    ACCP(1,  1,   3)
    ACCP(9,  35,  1)
    ACCP(13, 41,  3)
    ACCP(19, 65,  5)
    ACCP(35, 115, 3)
    ACCP(41, 139, 5)
  } else {                        // l2 = 2 : paths 2,6,8,9,12,14
    const int v = (c - 64) / 5, j = (c - 64) % 5;
    const int D2 = 5;
    ACCP(4,  10,  5)
    ACCP(16, 50,  3)
    ACCP(24, 80,  5)
    ACCP(29, 105, 1)
    ACCP(38, 124, 3)
    ACCP(46, 164, 5)
  }
}

// static-index readlane broadcast (VALU->SGPR; index MUST be a literal)
__device__ __forceinline__ float rl(float x, int l){
  return __int_as_float(__builtin_amdgcn_readlane(__float_as_int(x), l));
}

// ---------------------------------------------------------------------------
// fused5_kernel: block = 4 row-blocks of ONE config, 256 thr = 4 waves.
// U region (floats), manually overlaid:
//   phase A/B: [0,1512)=sB8 | [1512,1704)=sB1 | [1704,4968)=sT(4x816)
//              | [4968,9828)=sTPW_T(15x324, [p][v][u] transposed)
//   cart:      [0,9472)=sX2(64 rows x 148 pad, row-major float4)
//              | [9472,11776)=sOut(4x576)
// Total LDS: 47104(U) + 3072(sX1T) + 256(sCol) + 204(sMeta) ~ 50.6KB -> 3/CU.
// ---------------------------------------------------------------------------
__global__ __launch_bounds__(256, 3) void fused5_kernel(
    const float* __restrict__ feats,    // (4096, 144)
    const int*   __restrict__ layout,   // (E, 2)
    const float* __restrict__ tpw,      // (15, 16, 16)
    float*       __restrict__ out)      // (E, 9)
{
  __shared__ __align__(16) float U[11776];
  __shared__ __align__(16) float sX1T[4][192];
  __shared__ int sCol[64];
  __shared__ int sMeta[51];

  const int tid  = threadIdx.x;
  const int wave = tid >> 6;
  const int lane = tid & 63;
  const int rwBase = blockIdx.x * 4;             // 4 row-blocks, same config
  const int rw = rwBase + wave;

  float* sB8   = U;
  float* sB1   = U + 1512;
  float* sTPWT = U + 4968;

  // ---- stage shared tables (coalesced / tiny) ----
  for (int o = tid; o < 1512; o += 256) sB8[o] = cWQ.b8[o];
  if (tid < 189) sB1[tid] = cWQ.b1[tid];
  // tpw transposed: sTPWT[p*324 + v*20 + u] = tpw[p*256 + u*16 + v]
  for (int e = tid; e < 3840; e += 256){
    int p = e >> 8, r = e & 255, u = r >> 4, v = r & 15;
    sTPWT[p * 324 + v * 20 + u] = tpw[e];
  }
  if (tid < 51){
    int p = cC2P[tid], i = cC2I[tid], l1 = cP_L1[p];
    int xb = (l1 == 0) ? 0 : ((l1 == 1) ? 16 + i * 20 : 80 + i * 20);
    sMeta[tid] = xb | ((p * 324) << 16);
  }
  if (tid >= 192)                                // the config's 64 column nodes
    sCol[tid - 192] = layout[2 * ((size_t)rwBase * 64 + (tid - 192)) + 1];

  // ---- stage x1 TRANSPOSED per wave: l0 [0,16) | l1 rows 20 @16 | l2 @80 ----
  {
    int rn = layout[2 * (rw * 64)];
    rn = __builtin_amdgcn_readfirstlane(rn);
    const float* g = feats + (size_t)rn * 144;
    float* xt = sX1T[wave];
    if (lane < 16) xt[lane] = g[lane];                               // l=0
    if (lane < 48){ int i = lane >> 4, u = lane & 15;                // l=1
      xt[16 + i * 20 + u] = g[16 + u * 3 + i]; }
    { int i = lane >> 4, u = lane & 15;                              // l=2 i<4
      xt[80 + i * 20 + u] = g[64 + u * 5 + i]; }
    if (lane < 16) xt[160 + lane] = g[64 + lane * 5 + 4];            // l=2 i=4
  }
  __syncthreads();

  // ---- Phase A: t[c][v], 8x ds_read_b128 per c (same u-order as R9) ----
  float* pT = U + 1704 + wave * 816;
  {
    const int v  = lane & 15;
    const int cq = lane >> 4;
    const float* xw = sX1T[wave];
    #pragma unroll
    for (int it = 0; it < 13; ++it){
      int c = cq + it * 4;
      if (c < 51){
        int md = sMeta[c];
        const float* xb = xw + (md & 0xffff);
        const float* wb = sTPWT + (md >> 16) + v * 20;
        float s = 0.f;
        #pragma unroll
        for (int u4 = 0; u4 < 4; ++u4){
          float4 xv = *(const float4*)(xb + u4 * 4);
          float4 wv = *(const float4*)(wb + u4 * 4);
          s += xv.x * wv.x; s += xv.y * wv.y;
          s += xv.z * wv.z; s += xv.w * wv.w;
        }
        pT[c * 16 + v] = s;
      }
    }
  }
  // no barrier: pT wave-local

  // ---- Phase B: Mq -> REGISTERS (lane c holds c, c+64, c+128) ----
  float mq0[9], mq1[9], mq2[9];
  #pragma unroll
  for (int a = 0; a < 9; ++a) mq2[a] = 0.f;
  mqc(lane,      pT, sB8, sB1, mq0);
  mqc(lane + 64, pT, sB8, sB1, mq1);
  if (lane < 16) mqc(lane + 128, pT, sB8, sB1, mq2);
  __syncthreads();   // all waves done with sB8/sB1/pT before U is overlaid

  // ---- stage X2 row-major pad-148: row j at sX2[j*148] (37 f4 -> no swz) ---
  float* sX2 = U;
  #pragma unroll
  for (int k = 0; k < 9; ++k){
    int q = k * 256 + tid;                       // 0..2303 float4 tasks
    int j = q / 36, c4 = q - j * 36;
    const float4 xv = *(const float4*)(feats + (size_t)sCol[j] * 144 + c4 * 4);
    *(float4*)(sX2 + j * 148 + c4 * 4) = xv;
  }
  __syncthreads();

  // ---- cart: acc[a] = sum_c x2[j][c] * Mq[c][a]; Mq via STATIC readlane ----
  const float* xrow = sX2 + lane * 148;
  float acc[9];
  #pragma unroll
  for (int a = 0; a < 9; ++a) acc[a] = 0.f;

  #pragma unroll
  for (int c4 = 0; c4 < 36; ++c4){               // FULL unroll: c literal
    float4 xv = *(const float4*)(xrow + c4 * 4);
    #pragma unroll
    for (int r = 0; r < 4; ++r){
      const int c = c4 * 4 + r;
      float xs = (r == 0) ? xv.x : ((r == 1) ? xv.y : ((r == 2) ? xv.z : xv.w));
      #pragma unroll
      for (int a = 0; a < 9; ++a){
        float mv;
        if (c < 64)       mv = rl(mq0[a], c);
        else if (c < 128) mv = rl(mq1[a], c - 64);
        else              mv = rl(mq2[a], c - 128);
        acc[a] += xs * mv;
      }
    }
  }

  // ---- coalesced store via LDS staging (wave-local region of U) ----
  float* pO = U + 9472 + wave * 576;
  #pragma unroll
  for (int a = 0; a < 9; ++a) pO[lane * 9 + a] = acc[a];
  float* ob = out + (size_t)rw * 576;
  #pragma unroll
  for (int r = 0; r < 3; ++r){
    int idx = lane + r * 64;                     // float4 index 0..143
    if (idx < 144){
      float4 vv = *(const float4*)(pO + idx * 4);
      *(float4*)(ob + idx * 4) = vv;
    }
  }
}

// ---------------------------------------------------------------------------
// sym_tiled: 16x16 cell tile-pairs through LDS; fully coalesced; each element
// read+written exactly once. Block = (config b, tile-pair tp), 256 threads.
// ---------------------------------------------------------------------------
__global__ __launch_bounds__(256) void sym_tiled(float* __restrict__ out){
  __shared__ float sA[16 * 145];
  __shared__ float sB[16 * 145];
  const int tid = threadIdx.x;
  const int b  = blockIdx.x / 10;
  const int tp = blockIdx.x - b * 10;
  const int TI[10] = {0,0,0,0,1,1,1,2,2,3};
  const int TJ[10] = {0,1,2,3,1,2,3,2,3,3};
  const int ti = TI[tp], tj = TJ[tp];
  const bool diag = (ti == tj);
  const size_t cfgBase = (size_t)b * 4096 * 9;

  for (int idx = tid; idx < 2304; idx += 256){
    int r = idx / 144, off = idx - r * 144;
    sA[r * 145 + off] = out[cfgBase + ((size_t)(ti*16 + r) * 64 + tj*16) * 9 + off];
  }
  if (!diag){
    for (int idx = tid; idx < 2304; idx += 256){
      int r = idx / 144, off = idx - r * 144;
      sB[r * 145 + off] = out[cfgBase + ((size_t)(tj*16 + r) * 64 + ti*16) * 9 + off];
    }
  }
  __syncthreads();

  const int di = tid >> 4, dj = tid & 15;
  const float* A = sA;
  const float* B = diag ? sA : sB;
  float oa[9], ob[9];
  #pragma unroll
  for (int a = 0; a < 3; ++a)
    #pragma unroll
    for (int d = 0; d < 3; ++d){
      oa[a*3+d] = 0.5f * (A[di*145 + dj*9 + a*3+d] + B[dj*145 + di*9 + d*3+a]);
      if (!diag)
        ob[a*3+d] = 0.5f * (B[di*145 + dj*9 + a*3+d] + A[dj*145 + di*9 + d*3+a]);
    }
  __syncthreads();

  #pragma unroll
  for (int r9 = 0; r9 < 9; ++r9) sA[di*145 + dj*9 + r9] = oa[r9];
  if (!diag){
    #pragma unroll
    for (int r9 = 0; r9 < 9; ++r9) sB[di*145 + dj*9 + r9] = ob[r9];
  }
  __syncthreads();

  for (int idx = tid; idx < 2304; idx += 256){
    int r = idx / 144, off = idx - r * 144;
    out[cfgBase + ((size_t)(ti*16 + r) * 64 + tj*16) * 9 + off] = sA[r * 145 + off];
  }
  if (!diag){
    for (int idx = tid; idx < 2304; idx += 256){
      int r = idx / 144, off = idx - r * 144;
      out[cfgBase + ((size_t)(tj*16 + r) * 64 + ti*16) * 9 + off] = sB[r * 145 + off];
    }
  }
}

// ---------------------------------------------------------------------------
extern "C" void kernel_launch(void* const* d_in, const int* in_sizes, int n_in,
                              void* d_out, int out_size, void* d_ws, size_t ws_size,
                              hipStream_t stream) {
  const float* feats  = (const float*)d_in[0];   // (4096, 144)
  const int*   layout = (const int*)  d_in[1];   // (E, 2)
  const float* tpw    = (const float*)d_in[2];   // (15, 16, 16)
  float* out = (float*)d_out;
  (void)d_ws; (void)ws_size; (void)n_in; (void)out_size;

  const int E = in_sizes[1] / 2;                 // 262144
  const int R = E / 64;                          // 4096 row-blocks
  const int B = E / 4096;                        // 64 configs

  fused5_kernel<<<R / 4, 256, 0, stream>>>(feats, layout, tpw, out);
  sym_tiled<<<B * 10, 256, 0, stream>>>(out);
}

// Round 5
// 145.619 us; speedup vs baseline: 1.7328x; 1.7328x over previous
//
#include <hip/hip_runtime.h>
#include <math.h>

// ---------------------------------------------------------------------------
// IrrepsToHessian, round 13.
//
// R10/R12 (readlane-register Mq): scratch catastrophe (TCC 170-210MB). Family
// closed. R11 (intra-kernel global Mq, vector loads): latency-chained, slow.
// The ONE proven-fast Mq transport is R8's: Mq -> ws in kernel N, cart reads
// in kernel N+1 via wave-uniform pointer -> s_load (SMEM pipe, SGPR-operand
// FMAs, K$ invalidated at dispatch boundary).
//
// R13 = R8 split skeleton + proven upgrades:
//  - mq_kernel2: Phase A b128 (transposed x1/tpw, proven R11); each wave
//    does TWO row-blocks so wq/tpw LDS table reads amortize 2x (per-rb FMA
//    order unchanged -> bit-identical). Mq [c][12] -> ws (proven R11).
//  - cart_kernel2: s_load Mq (R8 idiom, #pragma unroll 8) + pad-148
//    row-major sX2 b128 x-reads (36 vs 576 DS/thread) + staged b128 out.
//  - sym_tiled unchanged. fused2 (R9, 46.5us) as no-ws fallback (pO fixed).
// ---------------------------------------------------------------------------

#define NPATH 15
#define MQ_ROW 12
#define MQ_STRIDE (144 * MQ_ROW)   // 1728 floats per row-block

// ======================= compile-time Wigner machinery =====================
constexpr double cfact(int n){ double r = 1.0; for (int i = 2; i <= n; ++i) r *= (double)i; return r; }
constexpr double csqrt(double x){
  if (x <= 0.0) return 0.0;
  double g = x < 1.0 ? 1.0 : x;
  for (int i = 0; i < 64; ++i) g = 0.5*(g + x/g);
  return g;
}

constexpr double ccg(int j1,int m1,int j2,int m2,int j3,int m3){
  if (m3 != m1 + m2) return 0.0;
  int vmin = -j1 + j2 + m3;
  if (-j1 + m1 > vmin) vmin = -j1 + m1;
  if (0 > vmin) vmin = 0;
  int vmax = j2 + j3 + m1;
  if (j3 - j1 + j2 < vmax) vmax = j3 - j1 + j2;
  if (j3 + m3 < vmax) vmax = j3 + m3;
  double C = csqrt((2.0*j3+1.0)*cfact(j3+j1-j2)*cfact(j3-j1+j2)*cfact(j1+j2-j3)
                   *cfact(j3+m3)*cfact(j3-m3)
                   /(cfact(j1+j2+j3+1)*cfact(j1-m1)*cfact(j1+m1)*cfact(j2-m2)*cfact(j2+m2)));
  double S = 0.0;
  for (int v = vmin; v <= vmax; ++v){
    double term = cfact(j2+j3+m1-v)*cfact(j1-m1+v)
                /(cfact(v)*cfact(j3-j1+j2-v)*cfact(j3+m3-v)*cfact(v+j1-j2-m3));
    S += ((v + j2 + m2) & 1) ? -term : term;
  }
  return C * S;
}

struct QM { double re[5][5]; double im[5][5]; };
constexpr QM cbuild_q(int l){
  QM q{};
  double s = 1.0 / csqrt(2.0);
  for (int m = -l; m < 0; ++m){
    q.re[l+m][l-m] = s;
    q.im[l+m][l+m] = -s;
  }
  q.re[l][l] = 1.0;
  for (int m = 1; m <= l; ++m){
    double sg = (m & 1) ? -1.0 : 1.0;
    q.re[l+m][l+m] = sg * s;
    q.im[l+m][l-m] = sg * s;
  }
  if (l == 1){           // * (-i): (a+bi) -> (b, -a)
    for (int r = 0; r < 5; ++r)
      for (int c = 0; c < 5; ++c){
        double a = q.re[r][c], b = q.im[r][c];
        q.re[r][c] = b; q.im[r][c] = -a;
      }
  } else if (l == 2){    // * (-1)
    for (int r = 0; r < 5; ++r)
      for (int c = 0; c < 5; ++c){ q.re[r][c] = -q.re[r][c]; q.im[r][c] = -q.im[r][c]; }
  }
  return q;
}

struct CRP { double v[125]; };   // normalized real w3j, [(i*d2+j)*d3+m]
constexpr CRP make_cr(int l1, int l2, int l3){
  QM q1 = cbuild_q(l1), q2 = cbuild_q(l2), q3 = cbuild_q(l3);
  const int d1 = 2*l1+1, d2 = 2*l2+1, d3 = 2*l3+1;
  double CG[125] = {};
  for (int i = 0; i < d1; ++i)
    for (int k = 0; k < d2; ++k)
      for (int m = 0; m < d3; ++m)
        CG[(i*5 + k)*5 + m] = ccg(l1, i-l1, l2, k-l2, l3, m-l3);
  CRP o{};
  for (int j = 0; j < d1; ++j)
    for (int l = 0; l < d2; ++l)
      for (int n = 0; n < d3; ++n){
        double acc = 0.0;
        for (int i = 0; i < d1; ++i)
          for (int k = 0; k < d2; ++k)
            for (int m = 0; m < d3; ++m){
              double c = CG[(i*5 + k)*5 + m];
              if (c == 0.0) continue;
              double are = q1.re[i][j], aim = q1.im[i][j];
              double bre = q2.re[k][l], bim = q2.im[k][l];
              double tre = are*bre - aim*bim;
              double tim = are*bim + aim*bre;
              double cre = q3.re[m][n], cim = q3.im[m][n];
              acc += (tre*cre + tim*cim) * c;   // Re( q1 q2 conj(q3) CG )
            }
        o.v[(j*d2 + l)*d3 + n] = acc;
      }
  double s2 = 0.0;
  for (int e = 0; e < d1*d2*d3; ++e) s2 += o.v[e]*o.v[e];
  double inv = 1.0 / csqrt(s2);
  for (int e = 0; e < d1*d2*d3; ++e) o.v[e] *= inv;
  return o;
}

constexpr CRP CR0  = make_cr(0,0,0);
constexpr CRP CR1  = make_cr(1,1,0);
constexpr CRP CR2  = make_cr(2,2,0);
constexpr CRP CR3  = make_cr(0,1,1);
constexpr CRP CR4  = make_cr(1,0,1);
constexpr CRP CR5  = make_cr(1,1,1);
constexpr CRP CR6  = make_cr(1,2,1);
constexpr CRP CR7  = make_cr(2,1,1);
constexpr CRP CR8  = make_cr(2,2,1);
constexpr CRP CR9  = make_cr(0,2,2);
constexpr CRP CR10 = make_cr(2,0,2);
constexpr CRP CR11 = make_cr(1,1,2);
constexpr CRP CR12 = make_cr(1,2,2);
constexpr CRP CR13 = make_cr(2,1,2);
constexpr CRP CR14 = make_cr(2,2,2);

struct QCT { double v[81]; };    // QCART[lm][i*3+j]
constexpr QCT make_qc(){
  QCT q{};
  for (int lm = 0; lm < 9; ++lm){
    int l = (lm == 0) ? 0 : ((lm < 4) ? 1 : 2);
    int m = lm - l*l;
    const CRP& cr = (l == 0) ? CR1 : ((l == 1) ? CR5 : CR11);  // paths (1,1,l)
    double sc = csqrt(2.0*l + 1.0);
    for (int r = 0; r < 9; ++r)
      q.v[lm*9 + r] = cr.v[r*(2*l+1) + m] * sc;
  }
  return q;
}
constexpr QCT QCt = make_qc();

// wq layout: 189 rows, split b8 (a<8) + b1 (a==8)
struct WQT { float b8[189*8]; float b1[189]; };
constexpr WQT make_wq(){
  WQT t{};
  const CRP* crs[NPATH] = {&CR0,&CR1,&CR2,&CR3,&CR4,&CR5,&CR6,&CR7,&CR8,&CR9,
                           &CR10,&CR11,&CR12,&CR13,&CR14};
  const int L1[NPATH]   = {0,1,2,0,1,1,1,2,2,0,2,1,1,2,2};
  const int L2[NPATH]   = {0,1,2,1,0,1,2,1,2,2,0,1,2,1,2};
  const int LO[NPATH]   = {0,0,0,1,1,1,1,1,1,2,2,2,2,2,2};
  const int PROW[NPATH] = {0,1,10,35,38,41,50,65,80,105,110,115,124,139,164};
  const double AL[3] = { csqrt(1.0/768.0), csqrt(3.0/1536.0), csqrt(5.0/1536.0) };
  for (int p = 0; p < NPATH; ++p){
    const int d1 = 2*L1[p]+1, d2 = 2*L2[p]+1, d3 = 2*LO[p]+1, lo = LO[p];
    for (int i = 0; i < d1; ++i)
      for (int j = 0; j < d2; ++j)
        for (int a = 0; a < 9; ++a){
          double acc = 0.0;
          for (int m = 0; m < d3; ++m)
            acc += crs[p]->v[(i*d2 + j)*d3 + m] * QCt.v[(lo*lo + m)*9 + a];
          double val = AL[lo] * acc;
          int row = PROW[p] + i*d2 + j;
          if (a < 8) t.b8[row*8 + a] = (float)val;
          else       t.b1[row]       = (float)val;
        }
  }
  return t;
}
__constant__ WQT cWQ = make_wq();

// ======================= runtime tables ====================================
__constant__ int cP_L1[NPATH]   = {0,1,2,0,1,1,1,2,2,0,2,1,1,2,2};
__constant__ int cC2P[51] = {0, 1,1,1, 2,2,2,2,2, 3, 4,4,4, 5,5,5, 6,6,6,
                             7,7,7,7,7, 8,8,8,8,8, 9, 10,10,10,10,10,
                             11,11,11, 12,12,12, 13,13,13,13,13, 14,14,14,14,14};
__constant__ int cC2I[51] = {0, 0,1,2, 0,1,2,3,4, 0, 0,1,2, 0,1,2, 0,1,2,
                             0,1,2,3,4, 0,1,2,3,4, 0, 0,1,2,3,4,
                             0,1,2, 0,1,2, 0,1,2,3,4, 0,1,2,3,4};

// ================= mq_kernel2: per-wave 2 row-blocks =======================
// LDS S layout (floats):
//   sB12  [0, 2268)      wq rows [189][12] (a0..a8, 3 pad)   (pad to 2272)
//   sTPWT [2272, 7132)   tpw transposed [p][v][u] stride 20  (pad to 7136)
//   pT    7136 + slot*816, slot in [0,8)   -> [7136, 13664)
//   sX1T  13664 + slot*192                 -> [13664, 15200)

// one path's contribution for one c, BOTH row-blocks (amortized table reads)
#define ACCP2(TOFF_, PROW_, D1_)                                             \
  { _Pragma("unroll")                                                        \
    for (int i = 0; i < (D1_); ++i){                                         \
      int row = (PROW_) + i * D2 + j;                                        \
      const float4 m0 = *(const float4*)&S[row * 12];                        \
      const float4 m1 = *(const float4*)&S[row * 12 + 4];                    \
      const float  m8 = S[row * 12 + 8];                                     \
      float tv0 = pT0[((TOFF_) + i) * 16 + v];                               \
      acc0[0] += tv0*m0.x; acc0[1] += tv0*m0.y; acc0[2] += tv0*m0.z;         \
      acc0[3] += tv0*m0.w; acc0[4] += tv0*m1.x; acc0[5] += tv0*m1.y;         \
      acc0[6] += tv0*m1.z; acc0[7] += tv0*m1.w; acc0[8] += tv0*m8;           \
      float tv1 = pT1[((TOFF_) + i) * 16 + v];                               \
      acc1[0] += tv1*m0.x; acc1[1] += tv1*m0.y; acc1[2] += tv1*m0.z;         \
      acc1[3] += tv1*m0.w; acc1[4] += tv1*m1.x; acc1[5] += tv1*m1.y;         \
      acc1[6] += tv1*m1.z; acc1[7] += tv1*m1.w; acc1[8] += tv1*m8;           \
    } }

__global__ __launch_bounds__(256, 2) void mq_kernel2(
    const float* __restrict__ feats,    // (4096, 144)
    const int*   __restrict__ layout,   // (E, 2)
    const float* __restrict__ tpw,      // (15, 16, 16)
    float*       __restrict__ mqg)      // ws: (R, 1728) Mq [c][12]
{
  __shared__ __align__(16) float S[15200];
  __shared__ int sMeta[51];

  const int tid  = threadIdx.x;
  const int wave = tid >> 6;
  const int lane = tid & 63;
  const int rb0  = blockIdx.x * 8 + wave * 2;    // wave's two row-blocks
  const int rb1  = rb0 + 1;

  // ---- stage tables ----
  for (int o = tid; o < 2268; o += 256){         // wq -> [row][12]
    int row = o / 12, k = o - row * 12;
    S[o] = (k < 8) ? cWQ.b8[row * 8 + k] : ((k == 8) ? cWQ.b1[row] : 0.f);
  }
  for (int e = tid; e < 3840; e += 256){         // tpw transposed
    int p = e >> 8, r = e & 255, u = r >> 4, v = r & 15;
    S[2272 + p * 324 + v * 20 + u] = tpw[e];
  }
  if (tid < 51){
    int p = cC2P[tid], i = cC2I[tid], l1 = cP_L1[p];
    int xb = (l1 == 0) ? 0 : ((l1 == 1) ? 16 + i * 20 : 80 + i * 20);
    sMeta[tid] = xb | ((p * 324) << 16);
  }
  // ---- stage x1 transposed, two row-blocks per wave ----
  #pragma unroll
  for (int sub = 0; sub < 2; ++sub){
    int rb = rb0 + sub;
    int rn = layout[2 * (rb * 64)];
    rn = __builtin_amdgcn_readfirstlane(rn);
    const float* g = feats + (size_t)rn * 144;
    float* xt = S + 13664 + (wave * 2 + sub) * 192;
    if (lane < 16) xt[lane] = g[lane];                               // l=0
    if (lane < 48){ int i = lane >> 4, u = lane & 15;                // l=1
      xt[16 + i * 20 + u] = g[16 + u * 3 + i]; }
    { int i = lane >> 4, u = lane & 15;                              // l=2 i<4
      xt[80 + i * 20 + u] = g[64 + u * 5 + i]; }
    if (lane < 16) xt[160 + lane] = g[64 + lane * 5 + 4];            // l=2 i=4
  }
  __syncthreads();

  // ---- Phase A: t[c][v] for both row-blocks; wb (tpw) read once ----
  float* pT0 = S + 7136 + (wave * 2 + 0) * 816;
  float* pT1 = S + 7136 + (wave * 2 + 1) * 816;
  {
    const int v  = lane & 15;
    const int cq = lane >> 4;
    const float* xw0 = S + 13664 + (wave * 2 + 0) * 192;
    const float* xw1 = S + 13664 + (wave * 2 + 1) * 192;
    #pragma unroll
    for (int it = 0; it < 13; ++it){
      int c = cq + it * 4;
      if (c < 51){
        int md = sMeta[c];
        int xo = md & 0xffff;
        const float* wb = S + 2272 + (md >> 16) + v * 20;
        float4 wv0 = *(const float4*)(wb);
        float4 wv1 = *(const float4*)(wb + 4);
        float4 wv2 = *(const float4*)(wb + 8);
        float4 wv3 = *(const float4*)(wb + 12);
        const float* xb0 = xw0 + xo;
        float s0 = 0.f;
        { float4 x0 = *(const float4*)(xb0);
          float4 x1 = *(const float4*)(xb0 + 4);
          float4 x2 = *(const float4*)(xb0 + 8);
          float4 x3 = *(const float4*)(xb0 + 12);
          s0 += x0.x*wv0.x; s0 += x0.y*wv0.y; s0 += x0.z*wv0.z; s0 += x0.w*wv0.w;
          s0 += x1.x*wv1.x; s0 += x1.y*wv1.y; s0 += x1.z*wv1.z; s0 += x1.w*wv1.w;
          s0 += x2.x*wv2.x; s0 += x2.y*wv2.y; s0 += x2.z*wv2.z; s0 += x2.w*wv2.w;
          s0 += x3.x*wv3.x; s0 += x3.y*wv3.y; s0 += x3.z*wv3.z; s0 += x3.w*wv3.w; }
        pT0[c * 16 + v] = s0;
        const float* xb1 = xw1 + xo;
        float s1 = 0.f;
        { float4 x0 = *(const float4*)(xb1);
          float4 x1 = *(const float4*)(xb1 + 4);
          float4 x2 = *(const float4*)(xb1 + 8);
          float4 x3 = *(const float4*)(xb1 + 12);
          s1 += x0.x*wv0.x; s1 += x0.y*wv0.y; s1 += x0.z*wv0.z; s1 += x0.w*wv0.w;
          s1 += x1.x*wv1.x; s1 += x1.y*wv1.y; s1 += x1.z*wv1.z; s1 += x1.w*wv1.w;
          s1 += x2.x*wv2.x; s1 += x2.y*wv2.y; s1 += x2.z*wv2.z; s1 += x2.w*wv2.w;
          s1 += x3.x*wv3.x; s1 += x3.y*wv3.y; s1 += x3.z*wv3.z; s1 += x3.w*wv3.w; }
        pT1[c * 16 + v] = s1;
      }
    }
  }
  // pT wave-local -> no barrier needed

  // ---- Phase B: Mq[c][a] for both row-blocks -> global ws ----
  float* __restrict__ mqw0 = mqg + (size_t)rb0 * MQ_STRIDE;
  float* __restrict__ mqw1 = mqg + (size_t)rb1 * MQ_STRIDE;
  for (int rnd = 0; rnd < 3; ++rnd){
    int c = lane + rnd * 64;
    if (c >= 144) break;
    float acc0[9], acc1[9];
    #pragma unroll
    for (int a = 0; a < 9; ++a){ acc0[a] = 0.f; acc1[a] = 0.f; }
    if (c < 16){                    // l2 = 0 : paths 0,4,10
      const int v = c, j = 0;
      const int D2 = 1;
      ACCP2(0,  0,   1)
      ACCP2(10, 38,  3)
      ACCP2(30, 110, 5)
    } else if (c < 64){             // l2 = 1 : paths 1,3,5,7,11,13
      const int v = (c - 16) / 3, j = (c - 16) % 3;
      const int D2 = 3;
      ACCP2(1,  1,   3)
      ACCP2(9,  35,  1)
      ACCP2(13, 41,  3)
      ACCP2(19, 65,  5)
      ACCP2(35, 115, 3)
      ACCP2(41, 139, 5)
    } else {                        // l2 = 2 : paths 2,6,8,9,12,14
      const int v = (c - 64) / 5, j = (c - 64) % 5;
      const int D2 = 5;
      ACCP2(4,  10,  5)
      ACCP2(16, 50,  3)
      ACCP2(24, 80,  5)
      ACCP2(29, 105, 1)
      ACCP2(38, 124, 3)
      ACCP2(46, 164, 5)
    }
    *(float4*)(mqw0 + c * MQ_ROW)     = make_float4(acc0[0], acc0[1], acc0[2], acc0[3]);
    *(float4*)(mqw0 + c * MQ_ROW + 4) = make_float4(acc0[4], acc0[5], acc0[6], acc0[7]);
    mqw0[c * MQ_ROW + 8] = acc0[8];
    *(float4*)(mqw1 + c * MQ_ROW)     = make_float4(acc1[0], acc1[1], acc1[2], acc1[3]);
    *(float4*)(mqw1 + c * MQ_ROW + 4) = make_float4(acc1[4], acc1[5], acc1[6], acc1[7]);
    mqw1[c * MQ_ROW + 8] = acc1[8];
  }
}

// ================= cart_kernel2: s_load Mq (R8 idiom) ======================
__global__ __launch_bounds__(256, 3) void cart_kernel2(
    const float* __restrict__ feats,
    const int*   __restrict__ layout,
    const float* __restrict__ mqg,      // (R, 1728) Mq [c][12]
    float*       __restrict__ out)
{
  __shared__ __align__(16) float sX2[64 * 148];  // 37888 B
  __shared__ __align__(16) float sOut[4][576];   //  9216 B
  __shared__ int sCol[64];
  const int tid  = threadIdx.x;
  const int wave = tid >> 6;
  const int lane = tid & 63;
  const int rwBase = blockIdx.x * 4;

  if (tid < 64) sCol[tid] = layout[2 * ((size_t)rwBase * 64 + tid) + 1];
  __syncthreads();

  // stage X2 row-major pad-148 (b128 writes, conflict-spread by stride 148)
  #pragma unroll
  for (int k = 0; k < 9; ++k){
    int q = k * 256 + tid;                       // 0..2303 float4 tasks
    int j = q / 36, c4 = q - j * 36;
    const float4 xv = *(const float4*)(feats + (size_t)sCol[j] * 144 + c4 * 4);
    *(float4*)(sX2 + j * 148 + c4 * 4) = xv;
  }
  __syncthreads();

  // wave-uniform Mq pointer -> compiler emits s_load; SGPR-operand FMAs
  const int rw = __builtin_amdgcn_readfirstlane(rwBase + wave);
  const float* __restrict__ mq = mqg + (size_t)rw * MQ_STRIDE;

  const float* xrow = sX2 + lane * 148;
  float acc[9];
  #pragma unroll
  for (int a = 0; a < 9; ++a) acc[a] = 0.f;

  #pragma unroll 8
  for (int c4 = 0; c4 < 36; ++c4){
    float4 xv = *(const float4*)(xrow + c4 * 4);
    #pragma unroll
    for (int r = 0; r < 4; ++r){
      int c = c4 * 4 + r;
      float xs = (r == 0) ? xv.x : ((r == 1) ? xv.y : ((r == 2) ? xv.z : xv.w));
      const float* mb = mq + c * MQ_ROW;
      acc[0] += xs * mb[0]; acc[1] += xs * mb[1]; acc[2] += xs * mb[2];
      acc[3] += xs * mb[3]; acc[4] += xs * mb[4]; acc[5] += xs * mb[5];
      acc[6] += xs * mb[6]; acc[7] += xs * mb[7]; acc[8] += xs * mb[8];
    }
  }

  // coalesced store via LDS staging (wave-local)
  float* pO = sOut[wave];
  #pragma unroll
  for (int a = 0; a < 9; ++a) pO[lane * 9 + a] = acc[a];
  float* ob = out + (size_t)(rwBase + wave) * 576;
  #pragma unroll
  for (int r = 0; r < 3; ++r){
    int idx = lane + r * 64;                     // float4 index 0..143
    if (idx < 144){
      float4 vv = *(const float4*)(pO + idx * 4);
      *(float4*)(ob + idx * 4) = vv;
    }
  }
}

// ================= fused2: R9 known-good fallback (no ws) ==================
#define ACCP(TOFF_, PROW_, D1_)                                              \
  { _Pragma("unroll")                                                        \
    for (int i = 0; i < (D1_); ++i){                                         \
      float tv = pT[((TOFF_) + i) * 16 + v];                                 \
      int row = (PROW_) + i * D2 + j;                                        \
      const float4 m0 = *(const float4*)&sB8[row * 8];                       \
      const float4 m1 = *(const float4*)&sB8[row * 8 + 4];                   \
      const float  m8 = sB1[row];                                            \
      acc[0] += tv*m0.x; acc[1] += tv*m0.y; acc[2] += tv*m0.z;               \
      acc[3] += tv*m0.w; acc[4] += tv*m1.x; acc[5] += tv*m1.y;               \
      acc[6] += tv*m1.z; acc[7] += tv*m1.w; acc[8] += tv*m8;                 \
    } }

__global__ __launch_bounds__(256, 2) void fused2_kernel(
    const float* __restrict__ feats,
    const int*   __restrict__ layout,
    const float* __restrict__ tpw,
    float*       __restrict__ out)
{
  __shared__ __align__(16) float U[11664];
  __shared__ __align__(16) float sMq[4][1728];
  __shared__ __align__(16) float sX1[4][144];
  __shared__ int sCol[64];

  const int tid  = threadIdx.x;
  const int wave = tid >> 6;
  const int lane = tid & 63;
  const int rwBase = blockIdx.x * 4;

  float* sB8  = U;
  float* sB1  = U + 1512;
  float* sTPW = U + 4968;

  for (int o = tid; o < 1512; o += 256) sB8[o] = cWQ.b8[o];
  if (tid < 189) sB1[tid] = cWQ.b1[tid];
  for (int q = tid; q < 960; q += 256)
    *(float4*)&sTPW[q * 4] = ((const float4*)tpw)[q];
  if (tid < 144){
    int w = tid / 36, q = tid - w * 36;
    int rn = layout[2 * ((rwBase + w) * 64)];
    *(float4*)&sX1[w][q * 4] = *(const float4*)(feats + (size_t)rn * 144 + q * 4);
  }
  if (tid >= 192)
    sCol[tid - 192] = layout[2 * ((size_t)rwBase * 64 + (tid - 192)) + 1];
  __syncthreads();

  float* pT = U + 1704 + wave * 816;
  {
    const int v  = lane & 15;
    const int cq = lane >> 4;
    const float* xw = sX1[wave];
    for (int it = 0; it < 13; ++it){
      int c = cq + it * 4;
      if (c < 51){
        int p = cC2P[c], i = cC2I[c];
        int l1 = cP_L1[p];
        int st = 2 * l1 + 1;
        int loff = (l1 == 0) ? 0 : ((l1 == 1) ? 16 : 64);
        const float* xb = xw + loff + i;
        const float* wb = sTPW + p * 256 + v;
        float s = 0.f;
        #pragma unroll
        for (int u = 0; u < 16; ++u) s += xb[u * st] * wb[u * 16];
        pT[c * 16 + v] = s;
      }
    }
  }

  float* pM = sMq[wave];
  for (int rnd = 0; rnd < 3; ++rnd){
    int c = lane + rnd * 64;
    if (c >= 144) break;
    float acc[9];
    #pragma unroll
    for (int a = 0; a < 9; ++a) acc[a] = 0.f;
    if (c < 16){
      const int v = c, j = 0;
      const int D2 = 1;
      ACCP(0,  0,   1)
      ACCP(10, 38,  3)
      ACCP(30, 110, 5)
    } else if (c < 64){
      const int v = (c - 16) / 3, j = (c - 16) % 3;
      const int D2 = 3;
      ACCP(1,  1,   3)
      ACCP(9,  35,  1)
      ACCP(13, 41,  3)
      ACCP(19, 65,  5)
      ACCP(35, 115, 3)
      ACCP(41, 139, 5)
    } else {
      const int v = (c - 64) / 5, j = (c - 64) % 5;
      const int D2 = 5;
      ACCP(4,  10,  5)
      ACCP(16, 50,  3)
      ACCP(24, 80,  5)
      ACCP(29, 105, 1)
      ACCP(38, 124, 3)
      ACCP(46, 164, 5)
    }
    *(float4*)&pM[c * 12]     = make_float4(acc[0], acc[1], acc[2], acc[3]);
    *(float4*)&pM[c * 12 + 4] = make_float4(acc[4], acc[5], acc[6], acc[7]);
    pM[c * 12 + 8] = acc[8];
  }
  __syncthreads();

  float* sX2T = U;
  #pragma unroll
  for (int k = 0; k < 9; ++k){
    int q = k * 256 + tid;
    int j = q / 36, c4 = q - j * 36;
    const float4 xv = *(const float4*)(feats + (size_t)sCol[j] * 144 + c4 * 4);
    int c0 = c4 * 4;
    sX2T[(c0 + 0) * 65 + j] = xv.x;
    sX2T[(c0 + 1) * 65 + j] = xv.y;
    sX2T[(c0 + 2) * 65 + j] = xv.z;
    sX2T[(c0 + 3) * 65 + j] = xv.w;
  }
  __syncthreads();

  float acc[9];
  #pragma unroll
  for (int a = 0; a < 9; ++a) acc[a] = 0.f;

  #pragma unroll 8
  for (int c = 0; c < 144; ++c){
    float x = sX2T[c * 65 + lane];
    const float4 m0 = *(const float4*)&pM[c * 12];
    const float4 m1 = *(const float4*)&pM[c * 12 + 4];
    const float  m8 = pM[c * 12 + 8];
    acc[0] += x * m0.x; acc[1] += x * m0.y; acc[2] += x * m0.z;
    acc[3] += x * m0.w; acc[4] += x * m1.x; acc[5] += x * m1.y;
    acc[6] += x * m1.z; acc[7] += x * m1.w; acc[8] += x * m8;
  }

  float* pO = U + 9360 + wave * 576;
  #pragma unroll
  for (int a = 0; a < 9; ++a) pO[lane * 9 + a] = acc[a];
  float* ob = out + (size_t)(rwBase + wave) * 576;
  #pragma unroll
  for (int r = 0; r < 3; ++r){
    int idx = lane + r * 64;
    if (idx < 144){
      float4 vv = *(const float4*)(pO + idx * 4);
      *(float4*)(ob + idx * 4) = vv;
    }
  }
}

// ---------------------------------------------------------------------------
// sym_tiled: 16x16 cell tile-pairs through LDS; fully coalesced; each element
// read+written exactly once. Block = (config b, tile-pair tp), 256 threads.
// ---------------------------------------------------------------------------
__global__ __launch_bounds__(256) void sym_tiled(float* __restrict__ out){
  __shared__ float sA[16 * 145];
  __shared__ float sB[16 * 145];
  const int tid = threadIdx.x;
  const int b  = blockIdx.x / 10;
  const int tp = blockIdx.x - b * 10;
  const int TI[10] = {0,0,0,0,1,1,1,2,2,3};
  const int TJ[10] = {0,1,2,3,1,2,3,2,3,3};
  const int ti = TI[tp], tj = TJ[tp];
  const bool diag = (ti == tj);
  const size_t cfgBase = (size_t)b * 4096 * 9;

  for (int idx = tid; idx < 2304; idx += 256){
    int r = idx / 144, off = idx - r * 144;
    sA[r * 145 + off] = out[cfgBase + ((size_t)(ti*16 + r) * 64 + tj*16) * 9 + off];
  }
  if (!diag){
    for (int idx = tid; idx < 2304; idx += 256){
      int r = idx / 144, off = idx - r * 144;
      sB[r * 145 + off] = out[cfgBase + ((size_t)(tj*16 + r) * 64 + ti*16) * 9 + off];
    }
  }
  __syncthreads();

  const int di = tid >> 4, dj = tid & 15;
  const float* A = sA;
  const float* B = diag ? sA : sB;
  float oa[9], ob[9];
  #pragma unroll
  for (int a = 0; a < 3; ++a)
    #pragma unroll
    for (int d = 0; d < 3; ++d){
      oa[a*3+d] = 0.5f * (A[di*145 + dj*9 + a*3+d] + B[dj*145 + di*9 + d*3+a]);
      if (!diag)
        ob[a*3+d] = 0.5f * (B[di*145 + dj*9 + a*3+d] + A[dj*145 + di*9 + d*3+a]);
    }
  __syncthreads();

  #pragma unroll
  for (int r9 = 0; r9 < 9; ++r9) sA[di*145 + dj*9 + r9] = oa[r9];
  if (!diag){
    #pragma unroll
    for (int r9 = 0; r9 < 9; ++r9) sB[di*145 + dj*9 + r9] = ob[r9];
  }
  __syncthreads();

  for (int idx = tid; idx < 2304; idx += 256){
    int r = idx / 144, off = idx - r * 144;
    out[cfgBase + ((size_t)(ti*16 + r) * 64 + tj*16) * 9 + off] = sA[r * 145 + off];
  }
  if (!diag){
    for (int idx = tid; idx < 2304; idx += 256){
      int r = idx / 144, off = idx - r * 144;
      out[cfgBase + ((size_t)(tj*16 + r) * 64 + ti*16) * 9 + off] = sB[r * 145 + off];
    }
  }
}

// ---------------------------------------------------------------------------
extern "C" void kernel_launch(void* const* d_in, const int* in_sizes, int n_in,
                              void* d_out, int out_size, void* d_ws, size_t ws_size,
                              hipStream_t stream) {
  const float* feats  = (const float*)d_in[0];   // (4096, 144)
  const int*   layout = (const int*)  d_in[1];   // (E, 2)
  const float* tpw    = (const float*)d_in[2];   // (15, 16, 16)
  float* out = (float*)d_out;
  float* ws  = (float*)d_ws;
  (void)n_in; (void)out_size;

  const int E = in_sizes[1] / 2;                 // 262144
  const int R = E / 64;                          // 4096 row-blocks
  const int B = E / 4096;                        // 64 configs

  const size_t need = (size_t)R * MQ_STRIDE * sizeof(float);
  if (ws_size >= need){
    mq_kernel2  <<<R / 8, 256, 0, stream>>>(feats, layout, tpw, ws);
    cart_kernel2<<<R / 4, 256, 0, stream>>>(feats, layout, ws, out);
  } else {
    fused2_kernel<<<R / 4, 256, 0, stream>>>(feats, layout, tpw, out);
  }
  sym_tiled<<<B * 10, 256, 0, stream>>>(out);
}

// Round 6
// 118.128 us; speedup vs baseline: 2.1360x; 1.2327x over previous
//
#include <hip/hip_runtime.h>
#include <math.h>

// ---------------------------------------------------------------------------
// IrrepsToHessian, round 14.
//
// Mq-transport verdict (R9-R13, all measured): LDS broadcast reads are the
// only fast path (same-address wave reads ~ 1 line, no 64-lane gather).
// s_load batched by SGPR pressure = latency chain (R13 cart 48.7us @ 11%
// VALU). readlane = spill catastrophe. vector-global = latency chain.
//
// R14 = single fused kernel (fused6):
//  - Phase A b128 (transposed x1/tpw; 3x proven, bit-identical).
//  - Phase B = R9 ACCP verbatim; Mq -> LDS region (bank-spread [2][144][4]
//    half-planes per rb; 8-way max on writes, conflict-free on reads).
//  - cart restructured: wave w owns c in [36w,36w+36); lane=(j-quad, rb).
//    Per c: 1 b128 x-read + 3 Mq reads serving ALL 4 row-blocks
//    -> 144 DS/wave (was 576). X2T stride 68 + XOR swizzle (j4^(c&3)).
//    Partial sums reduced via LDS stride-37; order ((w0+w1)+w2)+w3.
//  - Hand-overlaid LDS: 64.7KB -> 2 blocks/CU. No ws. 5 barriers.
// ---------------------------------------------------------------------------

#define NPATH 15

// ======================= compile-time Wigner machinery =====================
constexpr double cfact(int n){ double r = 1.0; for (int i = 2; i <= n; ++i) r *= (double)i; return r; }
constexpr double csqrt(double x){
  if (x <= 0.0) return 0.0;
  double g = x < 1.0 ? 1.0 : x;
  for (int i = 0; i < 64; ++i) g = 0.5*(g + x/g);
  return g;
}

constexpr double ccg(int j1,int m1,int j2,int m2,int j3,int m3){
  if (m3 != m1 + m2) return 0.0;
  int vmin = -j1 + j2 + m3;
  if (-j1 + m1 > vmin) vmin = -j1 + m1;
  if (0 > vmin) vmin = 0;
  int vmax = j2 + j3 + m1;
  if (j3 - j1 + j2 < vmax) vmax = j3 - j1 + j2;
  if (j3 + m3 < vmax) vmax = j3 + m3;
  double C = csqrt((2.0*j3+1.0)*cfact(j3+j1-j2)*cfact(j3-j1+j2)*cfact(j1+j2-j3)
                   *cfact(j3+m3)*cfact(j3-m3)
                   /(cfact(j1+j2+j3+1)*cfact(j1-m1)*cfact(j1+m1)*cfact(j2-m2)*cfact(j2+m2)));
  double S = 0.0;
  for (int v = vmin; v <= vmax; ++v){
    double term = cfact(j2+j3+m1-v)*cfact(j1-m1+v)
                /(cfact(v)*cfact(j3-j1+j2-v)*cfact(j3+m3-v)*cfact(v+j1-j2-m3));
    S += ((v + j2 + m2) & 1) ? -term : term;
  }
  return C * S;
}

struct QM { double re[5][5]; double im[5][5]; };
constexpr QM cbuild_q(int l){
  QM q{};
  double s = 1.0 / csqrt(2.0);
  for (int m = -l; m < 0; ++m){
    q.re[l+m][l-m] = s;
    q.im[l+m][l+m] = -s;
  }
  q.re[l][l] = 1.0;
  for (int m = 1; m <= l; ++m){
    double sg = (m & 1) ? -1.0 : 1.0;
    q.re[l+m][l+m] = sg * s;
    q.im[l+m][l-m] = sg * s;
  }
  if (l == 1){           // * (-i): (a+bi) -> (b, -a)
    for (int r = 0; r < 5; ++r)
      for (int c = 0; c < 5; ++c){
        double a = q.re[r][c], b = q.im[r][c];
        q.re[r][c] = b; q.im[r][c] = -a;
      }
  } else if (l == 2){    // * (-1)
    for (int r = 0; r < 5; ++r)
      for (int c = 0; c < 5; ++c){ q.re[r][c] = -q.re[r][c]; q.im[r][c] = -q.im[r][c]; }
  }
  return q;
}

struct CRP { double v[125]; };   // normalized real w3j, [(i*d2+j)*d3+m]
constexpr CRP make_cr(int l1, int l2, int l3){
  QM q1 = cbuild_q(l1), q2 = cbuild_q(l2), q3 = cbuild_q(l3);
  const int d1 = 2*l1+1, d2 = 2*l2+1, d3 = 2*l3+1;
  double CG[125] = {};
  for (int i = 0; i < d1; ++i)
    for (int k = 0; k < d2; ++k)
      for (int m = 0; m < d3; ++m)
        CG[(i*5 + k)*5 + m] = ccg(l1, i-l1, l2, k-l2, l3, m-l3);
  CRP o{};
  for (int j = 0; j < d1; ++j)
    for (int l = 0; l < d2; ++l)
      for (int n = 0; n < d3; ++n){
        double acc = 0.0;
        for (int i = 0; i < d1; ++i)
          for (int k = 0; k < d2; ++k)
            for (int m = 0; m < d3; ++m){
              double c = CG[(i*5 + k)*5 + m];
              if (c == 0.0) continue;
              double are = q1.re[i][j], aim = q1.im[i][j];
              double bre = q2.re[k][l], bim = q2.im[k][l];
              double tre = are*bre - aim*bim;
              double tim = are*bim + aim*bre;
              double cre = q3.re[m][n], cim = q3.im[m][n];
              acc += (tre*cre + tim*cim) * c;   // Re( q1 q2 conj(q3) CG )
            }
        o.v[(j*d2 + l)*d3 + n] = acc;
      }
  double s2 = 0.0;
  for (int e = 0; e < d1*d2*d3; ++e) s2 += o.v[e]*o.v[e];
  double inv = 1.0 / csqrt(s2);
  for (int e = 0; e < d1*d2*d3; ++e) o.v[e] *= inv;
  return o;
}

constexpr CRP CR0  = make_cr(0,0,0);
constexpr CRP CR1  = make_cr(1,1,0);
constexpr CRP CR2  = make_cr(2,2,0);
constexpr CRP CR3  = make_cr(0,1,1);
constexpr CRP CR4  = make_cr(1,0,1);
constexpr CRP CR5  = make_cr(1,1,1);
constexpr CRP CR6  = make_cr(1,2,1);
constexpr CRP CR7  = make_cr(2,1,1);
constexpr CRP CR8  = make_cr(2,2,1);
constexpr CRP CR9  = make_cr(0,2,2);
constexpr CRP CR10 = make_cr(2,0,2);
constexpr CRP CR11 = make_cr(1,1,2);
constexpr CRP CR12 = make_cr(1,2,2);
constexpr CRP CR13 = make_cr(2,1,2);
constexpr CRP CR14 = make_cr(2,2,2);

struct QCT { double v[81]; };    // QCART[lm][i*3+j]
constexpr QCT make_qc(){
  QCT q{};
  for (int lm = 0; lm < 9; ++lm){
    int l = (lm == 0) ? 0 : ((lm < 4) ? 1 : 2);
    int m = lm - l*l;
    const CRP& cr = (l == 0) ? CR1 : ((l == 1) ? CR5 : CR11);  // paths (1,1,l)
    double sc = csqrt(2.0*l + 1.0);
    for (int r = 0; r < 9; ++r)
      q.v[lm*9 + r] = cr.v[r*(2*l+1) + m] * sc;
  }
  return q;
}
constexpr QCT QCt = make_qc();

// wq layout: 189 rows, split b8 (a<8) + b1 (a==8)
struct WQT { float b8[189*8]; float b1[189]; };
constexpr WQT make_wq(){
  WQT t{};
  const CRP* crs[NPATH] = {&CR0,&CR1,&CR2,&CR3,&CR4,&CR5,&CR6,&CR7,&CR8,&CR9,
                           &CR10,&CR11,&CR12,&CR13,&CR14};
  const int L1[NPATH]   = {0,1,2,0,1,1,1,2,2,0,2,1,1,2,2};
  const int L2[NPATH]   = {0,1,2,1,0,1,2,1,2,2,0,1,2,1,2};
  const int LO[NPATH]   = {0,0,0,1,1,1,1,1,1,2,2,2,2,2,2};
  const int PROW[NPATH] = {0,1,10,35,38,41,50,65,80,105,110,115,124,139,164};
  const double AL[3] = { csqrt(1.0/768.0), csqrt(3.0/1536.0), csqrt(5.0/1536.0) };
  for (int p = 0; p < NPATH; ++p){
    const int d1 = 2*L1[p]+1, d2 = 2*L2[p]+1, d3 = 2*LO[p]+1, lo = LO[p];
    for (int i = 0; i < d1; ++i)
      for (int j = 0; j < d2; ++j)
        for (int a = 0; a < 9; ++a){
          double acc = 0.0;
          for (int m = 0; m < d3; ++m)
            acc += crs[p]->v[(i*d2 + j)*d3 + m] * QCt.v[(lo*lo + m)*9 + a];
          double val = AL[lo] * acc;
          int row = PROW[p] + i*d2 + j;
          if (a < 8) t.b8[row*8 + a] = (float)val;
          else       t.b1[row]       = (float)val;
        }
  }
  return t;
}
__constant__ WQT cWQ = make_wq();

// ======================= runtime tables ====================================
__constant__ int cP_L1[NPATH]   = {0,1,2,0,1,1,1,2,2,0,2,1,1,2,2};
__constant__ int cC2P[51] = {0, 1,1,1, 2,2,2,2,2, 3, 4,4,4, 5,5,5, 6,6,6,
                             7,7,7,7,7, 8,8,8,8,8, 9, 10,10,10,10,10,
                             11,11,11, 12,12,12, 13,13,13,13,13, 14,14,14,14,14};
__constant__ int cC2I[51] = {0, 0,1,2, 0,1,2,3,4, 0, 0,1,2, 0,1,2, 0,1,2,
                             0,1,2,3,4, 0,1,2,3,4, 0, 0,1,2,3,4,
                             0,1,2, 0,1,2, 0,1,2,3,4, 0,1,2,3,4};

// ---------------- LDS layout (floats) --------------------------------------
// Phase A/B:  WQ[189][12] @0 (2272) | pT 4x816 @2272 | TPWT 15x324 @5536
//             | X1T 4x192 @10400  -> ends 11168
// Mq (B->cart): MQA @11168: rb*1168 { [144][4] a0-3 ; @+584 [144][4] a4-7 }
//               MQB @15840: rb*152 + c (a8)          -> ends 16448
// cart:       X2T[144][68] @0 (9792, over WQ/pT/TPWT; XOR swz j4^(c&3))
// reduce:     RED @0: w*2368 + lane*37 + slot*9 + a (9472, over X2T)
// out:        SOUT @11168: rb*576 (over dead MQA)
#define WQ_OFF   0
#define PT_OFF   2272
#define TPWT_OFF 5536
#define X1T_OFF  10400
#define MQA_OFF  11168
#define MQA_RB   1168
#define MQA_H2   584
#define MQB_OFF  15840
#define MQB_RB   152
#define RED_W    2368
#define SOUT_OFF 11168
#define S_SIZE   16448

// ACCP: one path's contribution to acc[9] (reads pT, sB8, sB1, v, j, D2)
#define ACCP(TOFF_, PROW_, D1_)                                              \
  { _Pragma("unroll")                                                        \
    for (int i = 0; i < (D1_); ++i){                                         \
      float tv = pT[((TOFF_) + i) * 16 + v];                                 \
      int row = (PROW_) + i * D2 + j;                                        \
      const float4 m0 = *(const float4*)&sB8[row * 8];                       \
      const float4 m1 = *(const float4*)&sB8[row * 8 + 4];                   \
      const float  m8 = sB1[row];                                            \
      acc[0] += tv*m0.x; acc[1] += tv*m0.y; acc[2] += tv*m0.z;               \
      acc[3] += tv*m0.w; acc[4] += tv*m1.x; acc[5] += tv*m1.y;               \
      acc[6] += tv*m1.z; acc[7] += tv*m1.w; acc[8] += tv*m8;                 \
    } }

// ---------------------------------------------------------------------------
__global__ __launch_bounds__(256, 2) void fused6_kernel(
    const float* __restrict__ feats,    // (4096, 144)
    const int*   __restrict__ layout,   // (E, 2)
    const float* __restrict__ tpw,      // (15, 16, 16)
    float*       __restrict__ out)      // (E, 9)
{
  __shared__ __align__(16) float S[S_SIZE];
  __shared__ int sCol[64];
  __shared__ int sMeta[51];

  const int tid  = threadIdx.x;
  const int wave = tid >> 6;
  const int lane = tid & 63;
  const int rwBase = blockIdx.x * 4;             // 4 row-blocks, one config

  // ---- stage tables ----
  {
    float* wqd = S + WQ_OFF;                     // [189][12]: b8 | b1 | pad
    for (int o = tid; o < 2268; o += 256){
      int row = o / 12, k = o - row * 12;
      wqd[o] = (k < 8) ? cWQ.b8[row * 8 + k] : ((k == 8) ? cWQ.b1[row] : 0.f);
    }
  }
  for (int e = tid; e < 3840; e += 256){         // tpw transposed [p][v][u]
    int p = e >> 8, r = e & 255, u = r >> 4, v = r & 15;
    S[TPWT_OFF + p * 324 + v * 20 + u] = tpw[e];
  }
  if (tid < 51){
    int p = cC2P[tid], i = cC2I[tid], l1 = cP_L1[p];
    int xb = (l1 == 0) ? 0 : ((l1 == 1) ? 16 + i * 20 : 80 + i * 20);
    sMeta[tid] = xb | ((p * 324) << 16);
  }
  if (tid >= 192)                                // config's 64 column nodes
    sCol[tid - 192] = layout[2 * ((size_t)rwBase * 64 + (tid - 192)) + 1];

  // ---- stage x1 transposed per wave ----
  {
    int rn = layout[2 * ((rwBase + wave) * 64)];
    rn = __builtin_amdgcn_readfirstlane(rn);
    const float* g = feats + (size_t)rn * 144;
    float* xt = S + X1T_OFF + wave * 192;
    if (lane < 16) xt[lane] = g[lane];                               // l=0
    if (lane < 48){ int i = lane >> 4, u = lane & 15;                // l=1
      xt[16 + i * 20 + u] = g[16 + u * 3 + i]; }
    { int i = lane >> 4, u = lane & 15;                              // l=2 i<4
      xt[80 + i * 20 + u] = g[64 + u * 5 + i]; }
    if (lane < 16) xt[160 + lane] = g[64 + lane * 5 + 4];            // l=2 i=4
  }
  __syncthreads();                                                   // B1

  // ---- Phase A: t[c][v], 8x ds_read_b128 per c (R13-proven, bit-identical)
  float* pT = S + PT_OFF + wave * 816;
  {
    const int v  = lane & 15;
    const int cq = lane >> 4;
    const float* xw = S + X1T_OFF + wave * 192;
    #pragma unroll
    for (int it = 0; it < 13; ++it){
      int c = cq + it * 4;
      if (c < 51){
        int md = sMeta[c];
        const float* xb = xw + (md & 0xffff);
        const float* wb = S + TPWT_OFF + (md >> 16) + v * 20;
        float s = 0.f;
        #pragma unroll
        for (int u4 = 0; u4 < 4; ++u4){
          float4 xv = *(const float4*)(xb + u4 * 4);
          float4 wv = *(const float4*)(wb + u4 * 4);
          s += xv.x * wv.x; s += xv.y * wv.y;
          s += xv.z * wv.z; s += xv.w * wv.w;
        }
        pT[c * 16 + v] = s;
      }
    }
  }
  // pT wave-local: no barrier before Phase B (Mq region is disjoint)

  // ---- Phase B: Mq[c][a] -> LDS (R9 ACCP math verbatim) ----
  {
    const float* sB8 = S + WQ_OFF;       // stride-12 rows: 8 @ +0, a8 @ +8
    float* mqa = S + MQA_OFF + wave * MQA_RB;
    float* mqb = S + MQB_OFF + wave * MQB_RB;
    for (int rnd = 0; rnd < 3; ++rnd){
      int c = lane + rnd * 64;
      if (c >= 144) break;
      float acc[9];
      #pragma unroll
      for (int a = 0; a < 9; ++a) acc[a] = 0.f;
      // NOTE: sB8 here is the [189][12] table: row*8 accesses below must use
      // row*12; keep ACCP semantics via a shim pointer trick:
      {
        const float* pTl = pT;
        #define ACCPW(TOFF_, PROW_, D1_)                                     \
          { _Pragma("unroll")                                                \
            for (int i = 0; i < (D1_); ++i){                                 \
              float tv = pTl[((TOFF_) + i) * 16 + v];                        \
              int row = (PROW_) + i * D2 + j;                                \
              const float4 m0 = *(const float4*)&sB8[row * 12];              \
              const float4 m1 = *(const float4*)&sB8[row * 12 + 4];          \
              const float  m8 = sB8[row * 12 + 8];                           \
              acc[0] += tv*m0.x; acc[1] += tv*m0.y; acc[2] += tv*m0.z;       \
              acc[3] += tv*m0.w; acc[4] += tv*m1.x; acc[5] += tv*m1.y;       \
              acc[6] += tv*m1.z; acc[7] += tv*m1.w; acc[8] += tv*m8;         \
            } }
        if (c < 16){                    // l2 = 0 : paths 0,4,10
          const int v = c, j = 0;
          const int D2 = 1;
          ACCPW(0,  0,   1)
          ACCPW(10, 38,  3)
          ACCPW(30, 110, 5)
        } else if (c < 64){             // l2 = 1 : paths 1,3,5,7,11,13
          const int v = (c - 16) / 3, j = (c - 16) % 3;
          const int D2 = 3;
          ACCPW(1,  1,   3)
          ACCPW(9,  35,  1)
          ACCPW(13, 41,  3)
          ACCPW(19, 65,  5)
          ACCPW(35, 115, 3)
          ACCPW(41, 139, 5)
        } else {                        // l2 = 2 : paths 2,6,8,9,12,14
          const int v = (c - 64) / 5, j = (c - 64) % 5;
          const int D2 = 5;
          ACCPW(4,  10,  5)
          ACCPW(16, 50,  3)
          ACCPW(24, 80,  5)
          ACCPW(29, 105, 1)
          ACCPW(38, 124, 3)
          ACCPW(46, 164, 5)
        }
      }
      *(float4*)(mqa + c * 4)          = make_float4(acc[0], acc[1], acc[2], acc[3]);
      *(float4*)(mqa + MQA_H2 + c * 4) = make_float4(acc[4], acc[5], acc[6], acc[7]);
      mqb[c] = acc[8];
    }
  }
  __syncthreads();                                                   // B2

  // ---- stage X2 transposed [c][68], XOR-swizzled (over WQ/pT/TPWT) ----
  #pragma unroll
  for (int k = 0; k < 9; ++k){
    int q = k * 256 + tid;                       // 0..2303 float4 tasks
    int j = q / 36, c4 = q - j * 36;
    const float4 xv = *(const float4*)(feats + (size_t)sCol[j] * 144 + c4 * 4);
    int j4 = j >> 2, jl = j & 3;
    #pragma unroll
    for (int t = 0; t < 4; ++t){
      int c = c4 * 4 + t;
      float xs = (t == 0) ? xv.x : ((t == 1) ? xv.y : ((t == 2) ? xv.z : xv.w));
      S[c * 68 + ((j4 ^ (c & 3)) << 2) + jl] = xs;
    }
  }
  __syncthreads();                                                   // B3

  // ---- cart: wave w owns c in [36w, 36w+36); lane = (jg, rb) ----
  const int jg  = lane & 15;
  const int rbq = lane >> 4;
  const float* mqa = S + MQA_OFF + rbq * MQA_RB;
  const float* mqb = S + MQB_OFF + rbq * MQB_RB;
  float acc[4][9];
  #pragma unroll
  for (int jj = 0; jj < 4; ++jj)
    #pragma unroll
    for (int a = 0; a < 9; ++a) acc[jj][a] = 0.f;

  {
    const int c0 = wave * 36;
    #pragma unroll 4
    for (int cc = 0; cc < 36; ++cc){
      int c = c0 + cc;
      float4 xv = *(const float4*)&S[c * 68 + ((jg ^ (c & 3)) << 2)];
      float4 m0 = *(const float4*)(mqa + c * 4);
      float4 m1 = *(const float4*)(mqa + MQA_H2 + c * 4);
      float  m8 = mqb[c];
      #pragma unroll
      for (int jj = 0; jj < 4; ++jj){
        float xs = (jj == 0) ? xv.x : ((jj == 1) ? xv.y : ((jj == 2) ? xv.z : xv.w));
        acc[jj][0] += xs * m0.x; acc[jj][1] += xs * m0.y;
        acc[jj][2] += xs * m0.z; acc[jj][3] += xs * m0.w;
        acc[jj][4] += xs * m1.x; acc[jj][5] += xs * m1.y;
        acc[jj][6] += xs * m1.z; acc[jj][7] += xs * m1.w;
        acc[jj][8] += xs * m8;
      }
    }
  }
  __syncthreads();                                                   // B4

  // ---- write partials: RED[w][lane][slot*9+a], stride 37 ----
  {
    float* rb = S + wave * RED_W + lane * 37;
    #pragma unroll
    for (int jj = 0; jj < 4; ++jj)
      #pragma unroll
      for (int a = 0; a < 9; ++a) rb[jj * 9 + a] = acc[jj][a];
  }
  __syncthreads();                                                   // B5

  // ---- reduce + store: thread t -> (rb = t>>6, j = t&63) ----
  {
    const int rbo = wave;                        // output row-block
    const int j   = lane;
    const int lp  = (j >> 2) | (rbo << 4);       // cart lane holding (rb,j)
    const int sl  = j & 3;
    const float* r0 = S + 0 * RED_W + lp * 37 + sl * 9;
    const float* r1 = S + 1 * RED_W + lp * 37 + sl * 9;
    const float* r2 = S + 2 * RED_W + lp * 37 + sl * 9;
    const float* r3 = S + 3 * RED_W + lp * 37 + sl * 9;
    float* pO = S + SOUT_OFF + rbo * 576;
    #pragma unroll
    for (int a = 0; a < 9; ++a)
      pO[j * 9 + a] = ((r0[a] + r1[a]) + r2[a]) + r3[a];
    // wave-local staging -> coalesced b128 store
    float* ob = out + (size_t)(rwBase + rbo) * 576;
    #pragma unroll
    for (int r = 0; r < 3; ++r){
      int idx = lane + r * 64;                   // float4 index 0..143
      if (idx < 144){
        float4 vv = *(const float4*)(pO + idx * 4);
        *(float4*)(ob + idx * 4) = vv;
      }
    }
  }
}

// ---------------------------------------------------------------------------
// sym_tiled: 16x16 cell tile-pairs through LDS; fully coalesced; each element
// read+written exactly once. Block = (config b, tile-pair tp), 256 threads.
// ---------------------------------------------------------------------------
__global__ __launch_bounds__(256) void sym_tiled(float* __restrict__ out){
  __shared__ float sA[16 * 145];
  __shared__ float sB[16 * 145];
  const int tid = threadIdx.x;
  const int b  = blockIdx.x / 10;
  const int tp = blockIdx.x - b * 10;
  const int TI[10] = {0,0,0,0,1,1,1,2,2,3};
  const int TJ[10] = {0,1,2,3,1,2,3,2,3,3};
  const int ti = TI[tp], tj = TJ[tp];
  const bool diag = (ti == tj);
  const size_t cfgBase = (size_t)b * 4096 * 9;

  for (int idx = tid; idx < 2304; idx += 256){
    int r = idx / 144, off = idx - r * 144;
    sA[r * 145 + off] = out[cfgBase + ((size_t)(ti*16 + r) * 64 + tj*16) * 9 + off];
  }
  if (!diag){
    for (int idx = tid; idx < 2304; idx += 256){
      int r = idx / 144, off = idx - r * 144;
      sB[r * 145 + off] = out[cfgBase + ((size_t)(tj*16 + r) * 64 + ti*16) * 9 + off];
    }
  }
  __syncthreads();

  const int di = tid >> 4, dj = tid & 15;
  const float* A = sA;
  const float* B = diag ? sA : sB;
  float oa[9], ob[9];
  #pragma unroll
  for (int a = 0; a < 3; ++a)
    #pragma unroll
    for (int d = 0; d < 3; ++d){
      oa[a*3+d] = 0.5f * (A[di*145 + dj*9 + a*3+d] + B[dj*145 + di*9 + d*3+a]);
      if (!diag)
        ob[a*3+d] = 0.5f * (B[di*145 + dj*9 + a*3+d] + A[dj*145 + di*9 + d*3+a]);
    }
  __syncthreads();

  #pragma unroll
  for (int r9 = 0; r9 < 9; ++r9) sA[di*145 + dj*9 + r9] = oa[r9];
  if (!diag){
    #pragma unroll
    for (int r9 = 0; r9 < 9; ++r9) sB[di*145 + dj*9 + r9] = ob[r9];
  }
  __syncthreads();

  for (int idx = tid; idx < 2304; idx += 256){
    int r = idx / 144, off = idx - r * 144;
    out[cfgBase + ((size_t)(ti*16 + r) * 64 + tj*16) * 9 + off] = sA[r * 145 + off];
  }
  if (!diag){
    for (int idx = tid; idx < 2304; idx += 256){
      int r = idx / 144, off = idx - r * 144;
      out[cfgBase + ((size_t)(tj*16 + r) * 64 + ti*16) * 9 + off] = sB[r * 145 + off];
    }
  }
}

// ---------------------------------------------------------------------------
extern "C" void kernel_launch(void* const* d_in, const int* in_sizes, int n_in,
                              void* d_out, int out_size, void* d_ws, size_t ws_size,
                              hipStream_t stream) {
  const float* feats  = (const float*)d_in[0];   // (4096, 144)
  const int*   layout = (const int*)  d_in[1];   // (E, 2)
  const float* tpw    = (const float*)d_in[2];   // (15, 16, 16)
  float* out = (float*)d_out;
  (void)d_ws; (void)ws_size; (void)n_in; (void)out_size;

  const int E = in_sizes[1] / 2;                 // 262144
  const int R = E / 64;                          // 4096 row-blocks
  const int B = E / 4096;                        // 64 configs

  fused6_kernel<<<R / 4, 256, 0, stream>>>(feats, layout, tpw, out);
  sym_tiled<<<B * 10, 256, 0, stream>>>(out);
}

// Round 7
// 112.820 us; speedup vs baseline: 2.2365x; 1.0471x over previous
//
#include <hip/hip_runtime.h>
#include <math.h>

// ---------------------------------------------------------------------------
// IrrepsToHessian, round 15.
//
// R14 post-mortem: fused6's staging "swizzle" used c&3 == t == constant per
// instruction -> 18-way bank conflict on X2T staging (conflicts 1.2M->4.1M),
// +2 barriers -> 54us. Wave-c-split cart shelved.
//
// R15 (fused8) = fused2 (46.5us, proven) + the two individually-proven,
// bit-identical DS reductions:
//  1. Phase A b128: transposed x1/tpw in LDS (R11/R12/R13 passes).
//     416 ds_read_b32 -> 104 ds_read_b128.
//  2. X2 row-major pad-148 (R12/R13, ~zero conflicts): staging 36 b128
//     conflict-free writes; cart x = 36 b128 reads (was 144 b32).
//  cart Mq = fused2's LDS broadcast reads verbatim (only transport that
//  never regressed). Accumulation order identical -> absmax unchanged.
// LDS 78.3KB -> 2 blocks/CU. No ws. 3 barriers (same as fused2).
// ---------------------------------------------------------------------------

#define NPATH 15

// ======================= compile-time Wigner machinery =====================
constexpr double cfact(int n){ double r = 1.0; for (int i = 2; i <= n; ++i) r *= (double)i; return r; }
constexpr double csqrt(double x){
  if (x <= 0.0) return 0.0;
  double g = x < 1.0 ? 1.0 : x;
  for (int i = 0; i < 64; ++i) g = 0.5*(g + x/g);
  return g;
}

constexpr double ccg(int j1,int m1,int j2,int m2,int j3,int m3){
  if (m3 != m1 + m2) return 0.0;
  int vmin = -j1 + j2 + m3;
  if (-j1 + m1 > vmin) vmin = -j1 + m1;
  if (0 > vmin) vmin = 0;
  int vmax = j2 + j3 + m1;
  if (j3 - j1 + j2 < vmax) vmax = j3 - j1 + j2;
  if (j3 + m3 < vmax) vmax = j3 + m3;
  double C = csqrt((2.0*j3+1.0)*cfact(j3+j1-j2)*cfact(j3-j1+j2)*cfact(j1+j2-j3)
                   *cfact(j3+m3)*cfact(j3-m3)
                   /(cfact(j1+j2+j3+1)*cfact(j1-m1)*cfact(j1+m1)*cfact(j2-m2)*cfact(j2+m2)));
  double S = 0.0;
  for (int v = vmin; v <= vmax; ++v){
    double term = cfact(j2+j3+m1-v)*cfact(j1-m1+v)
                /(cfact(v)*cfact(j3-j1+j2-v)*cfact(j3+m3-v)*cfact(v+j1-j2-m3));
    S += ((v + j2 + m2) & 1) ? -term : term;
  }
  return C * S;
}

struct QM { double re[5][5]; double im[5][5]; };
constexpr QM cbuild_q(int l){
  QM q{};
  double s = 1.0 / csqrt(2.0);
  for (int m = -l; m < 0; ++m){
    q.re[l+m][l-m] = s;
    q.im[l+m][l+m] = -s;
  }
  q.re[l][l] = 1.0;
  for (int m = 1; m <= l; ++m){
    double sg = (m & 1) ? -1.0 : 1.0;
    q.re[l+m][l+m] = sg * s;
    q.im[l+m][l-m] = sg * s;
  }
  if (l == 1){           // * (-i): (a+bi) -> (b, -a)
    for (int r = 0; r < 5; ++r)
      for (int c = 0; c < 5; ++c){
        double a = q.re[r][c], b = q.im[r][c];
        q.re[r][c] = b; q.im[r][c] = -a;
      }
  } else if (l == 2){    // * (-1)
    for (int r = 0; r < 5; ++r)
      for (int c = 0; c < 5; ++c){ q.re[r][c] = -q.re[r][c]; q.im[r][c] = -q.im[r][c]; }
  }
  return q;
}

struct CRP { double v[125]; };   // normalized real w3j, [(i*d2+j)*d3+m]
constexpr CRP make_cr(int l1, int l2, int l3){
  QM q1 = cbuild_q(l1), q2 = cbuild_q(l2), q3 = cbuild_q(l3);
  const int d1 = 2*l1+1, d2 = 2*l2+1, d3 = 2*l3+1;
  double CG[125] = {};
  for (int i = 0; i < d1; ++i)
    for (int k = 0; k < d2; ++k)
      for (int m = 0; m < d3; ++m)
        CG[(i*5 + k)*5 + m] = ccg(l1, i-l1, l2, k-l2, l3, m-l3);
  CRP o{};
  for (int j = 0; j < d1; ++j)
    for (int l = 0; l < d2; ++l)
      for (int n = 0; n < d3; ++n){
        double acc = 0.0;
        for (int i = 0; i < d1; ++i)
          for (int k = 0; k < d2; ++k)
            for (int m = 0; m < d3; ++m){
              double c = CG[(i*5 + k)*5 + m];
              if (c == 0.0) continue;
              double are = q1.re[i][j], aim = q1.im[i][j];
              double bre = q2.re[k][l], bim = q2.im[k][l];
              double tre = are*bre - aim*bim;
              double tim = are*bim + aim*bre;
              double cre = q3.re[m][n], cim = q3.im[m][n];
              acc += (tre*cre + tim*cim) * c;   // Re( q1 q2 conj(q3) CG )
            }
        o.v[(j*d2 + l)*d3 + n] = acc;
      }
  double s2 = 0.0;
  for (int e = 0; e < d1*d2*d3; ++e) s2 += o.v[e]*o.v[e];
  double inv = 1.0 / csqrt(s2);
  for (int e = 0; e < d1*d2*d3; ++e) o.v[e] *= inv;
  return o;
}

constexpr CRP CR0  = make_cr(0,0,0);
constexpr CRP CR1  = make_cr(1,1,0);
constexpr CRP CR2  = make_cr(2,2,0);
constexpr CRP CR3  = make_cr(0,1,1);
constexpr CRP CR4  = make_cr(1,0,1);
constexpr CRP CR5  = make_cr(1,1,1);
constexpr CRP CR6  = make_cr(1,2,1);
constexpr CRP CR7  = make_cr(2,1,1);
constexpr CRP CR8  = make_cr(2,2,1);
constexpr CRP CR9  = make_cr(0,2,2);
constexpr CRP CR10 = make_cr(2,0,2);
constexpr CRP CR11 = make_cr(1,1,2);
constexpr CRP CR12 = make_cr(1,2,2);
constexpr CRP CR13 = make_cr(2,1,2);
constexpr CRP CR14 = make_cr(2,2,2);

struct QCT { double v[81]; };    // QCART[lm][i*3+j]
constexpr QCT make_qc(){
  QCT q{};
  for (int lm = 0; lm < 9; ++lm){
    int l = (lm == 0) ? 0 : ((lm < 4) ? 1 : 2);
    int m = lm - l*l;
    const CRP& cr = (l == 0) ? CR1 : ((l == 1) ? CR5 : CR11);  // paths (1,1,l)
    double sc = csqrt(2.0*l + 1.0);
    for (int r = 0; r < 9; ++r)
      q.v[lm*9 + r] = cr.v[r*(2*l+1) + m] * sc;
  }
  return q;
}
constexpr QCT QCt = make_qc();

// wq layout: 189 rows, split b8 (a<8) + b1 (a==8)
struct WQT { float b8[189*8]; float b1[189]; };
constexpr WQT make_wq(){
  WQT t{};
  const CRP* crs[NPATH] = {&CR0,&CR1,&CR2,&CR3,&CR4,&CR5,&CR6,&CR7,&CR8,&CR9,
                           &CR10,&CR11,&CR12,&CR13,&CR14};
  const int L1[NPATH]   = {0,1,2,0,1,1,1,2,2,0,2,1,1,2,2};
  const int L2[NPATH]   = {0,1,2,1,0,1,2,1,2,2,0,1,2,1,2};
  const int LO[NPATH]   = {0,0,0,1,1,1,1,1,1,2,2,2,2,2,2};
  const int PROW[NPATH] = {0,1,10,35,38,41,50,65,80,105,110,115,124,139,164};
  const double AL[3] = { csqrt(1.0/768.0), csqrt(3.0/1536.0), csqrt(5.0/1536.0) };
  for (int p = 0; p < NPATH; ++p){
    const int d1 = 2*L1[p]+1, d2 = 2*L2[p]+1, d3 = 2*LO[p]+1, lo = LO[p];
    for (int i = 0; i < d1; ++i)
      for (int j = 0; j < d2; ++j)
        for (int a = 0; a < 9; ++a){
          double acc = 0.0;
          for (int m = 0; m < d3; ++m)
            acc += crs[p]->v[(i*d2 + j)*d3 + m] * QCt.v[(lo*lo + m)*9 + a];
          double val = AL[lo] * acc;
          int row = PROW[p] + i*d2 + j;
          if (a < 8) t.b8[row*8 + a] = (float)val;
          else       t.b1[row]       = (float)val;
        }
  }
  return t;
}
__constant__ WQT cWQ = make_wq();

// ======================= runtime tables ====================================
__constant__ int cP_L1[NPATH]   = {0,1,2,0,1,1,1,2,2,0,2,1,1,2,2};
__constant__ int cC2P[51] = {0, 1,1,1, 2,2,2,2,2, 3, 4,4,4, 5,5,5, 6,6,6,
                             7,7,7,7,7, 8,8,8,8,8, 9, 10,10,10,10,10,
                             11,11,11, 12,12,12, 13,13,13,13,13, 14,14,14,14,14};
__constant__ int cC2I[51] = {0, 0,1,2, 0,1,2,3,4, 0, 0,1,2, 0,1,2, 0,1,2,
                             0,1,2,3,4, 0,1,2,3,4, 0, 0,1,2,3,4,
                             0,1,2, 0,1,2, 0,1,2,3,4, 0,1,2,3,4};

// ACCP: one path's contribution to acc[9] (reads pT, sB8, sB1, v, j, D2)
#define ACCP(TOFF_, PROW_, D1_)                                              \
  { _Pragma("unroll")                                                        \
    for (int i = 0; i < (D1_); ++i){                                         \
      float tv = pT[((TOFF_) + i) * 16 + v];                                 \
      int row = (PROW_) + i * D2 + j;                                        \
      const float4 m0 = *(const float4*)&sB8[row * 8];                       \
      const float4 m1 = *(const float4*)&sB8[row * 8 + 4];                   \
      const float  m8 = sB1[row];                                            \
      acc[0] += tv*m0.x; acc[1] += tv*m0.y; acc[2] += tv*m0.z;               \
      acc[3] += tv*m0.w; acc[4] += tv*m1.x; acc[5] += tv*m1.y;               \
      acc[6] += tv*m1.z; acc[7] += tv*m1.w; acc[8] += tv*m8;                 \
    } }

// ---------------------------------------------------------------------------
// fused8_kernel: block = 4 row-blocks of ONE config, 256 thr = 4 waves.
// U region (floats), manually overlaid:
//   phase A/B: [0,1512)=sB8 | [1512,1704)=sB1 | [1704,4968)=pT(4x816)
//              | [4968,9828)=sTPWT(15x324, [p][v][u] stride 20)
//   cart:      [0,9472)=sX2R(64 rows x 148 pad, row-major float4)
//              | [9472,11776)=sOut(4x576)
// Static: U 47104B + sMq 27648B + sX1T 3072B + sCol 256B + sMeta 204B
//       = 78.3KB -> 2 blocks/CU.
// ---------------------------------------------------------------------------
__global__ __launch_bounds__(256, 2) void fused8_kernel(
    const float* __restrict__ feats,    // (4096, 144)
    const int*   __restrict__ layout,   // (E, 2)
    const float* __restrict__ tpw,      // (15, 16, 16)
    float*       __restrict__ out)      // (E, 9)
{
  __shared__ __align__(16) float U[11776];
  __shared__ __align__(16) float sMq[4][1728];   // Mq [c][12] per wave
  __shared__ __align__(16) float sX1T[4][192];
  __shared__ int sCol[64];
  __shared__ int sMeta[51];

  const int tid  = threadIdx.x;
  const int wave = tid >> 6;
  const int lane = tid & 63;
  const int rwBase = blockIdx.x * 4;             // 4 row-blocks, same config
  const int rw = rwBase + wave;

  float* sB8   = U;
  float* sB1   = U + 1512;
  float* sTPWT = U + 4968;

  // ---- stage shared tables (coalesced / tiny) ----
  for (int o = tid; o < 1512; o += 256) sB8[o] = cWQ.b8[o];
  if (tid < 189) sB1[tid] = cWQ.b1[tid];
  // tpw transposed: sTPWT[p*324 + v*20 + u] = tpw[p*256 + u*16 + v]
  for (int e = tid; e < 3840; e += 256){
    int p = e >> 8, r = e & 255, u = r >> 4, v = r & 15;
    sTPWT[p * 324 + v * 20 + u] = tpw[e];
  }
  if (tid < 51){
    int p = cC2P[tid], i = cC2I[tid], l1 = cP_L1[p];
    int xb = (l1 == 0) ? 0 : ((l1 == 1) ? 16 + i * 20 : 80 + i * 20);
    sMeta[tid] = xb | ((p * 324) << 16);
  }
  if (tid >= 192)                                // the config's 64 column nodes
    sCol[tid - 192] = layout[2 * ((size_t)rwBase * 64 + (tid - 192)) + 1];

  // ---- stage x1 TRANSPOSED per wave: l0 [0,16) | l1 rows 20 @16 | l2 @80 ----
  {
    int rn = layout[2 * (rw * 64)];
    rn = __builtin_amdgcn_readfirstlane(rn);
    const float* g = feats + (size_t)rn * 144;
    float* xt = sX1T[wave];
    if (lane < 16) xt[lane] = g[lane];                               // l=0
    if (lane < 48){ int i = lane >> 4, u = lane & 15;                // l=1
      xt[16 + i * 20 + u] = g[16 + u * 3 + i]; }
    { int i = lane >> 4, u = lane & 15;                              // l=2 i<4
      xt[80 + i * 20 + u] = g[64 + u * 5 + i]; }
    if (lane < 16) xt[160 + lane] = g[64 + lane * 5 + 4];            // l=2 i=4
  }
  __syncthreads();

  // ---- Phase A: t[c][v], 8x ds_read_b128 per c (same u-order -> identical)
  float* pT = U + 1704 + wave * 816;
  {
    const int v  = lane & 15;
    const int cq = lane >> 4;
    const float* xw = sX1T[wave];
    #pragma unroll
    for (int it = 0; it < 13; ++it){
      int c = cq + it * 4;
      if (c < 51){
        int md = sMeta[c];
        const float* xb = xw + (md & 0xffff);
        const float* wb = sTPWT + (md >> 16) + v * 20;
        float s = 0.f;
        #pragma unroll
        for (int u4 = 0; u4 < 4; ++u4){
          float4 xv = *(const float4*)(xb + u4 * 4);
          float4 wv = *(const float4*)(wb + u4 * 4);
          s += xv.x * wv.x; s += xv.y * wv.y;
          s += xv.z * wv.z; s += xv.w * wv.w;
        }
        pT[c * 16 + v] = s;
      }
    }
  }
  // no barrier: pT wave-local; sMq region disjoint from staged tables

  // ---- Phase B: Mq[c][a] -> sMq[wave] (fused2 math verbatim) ----
  float* pM = sMq[wave];
  for (int rnd = 0; rnd < 3; ++rnd){
    int c = lane + rnd * 64;
    if (c >= 144) break;
    float acc[9];
    #pragma unroll
    for (int a = 0; a < 9; ++a) acc[a] = 0.f;
    if (c < 16){                    // l2 = 0 : paths 0,4,10
      const int v = c, j = 0;
      const int D2 = 1;
      ACCP(0,  0,   1)
      ACCP(10, 38,  3)
      ACCP(30, 110, 5)
    } else if (c < 64){             // l2 = 1 : paths 1,3,5,7,11,13
      const int v = (c - 16) / 3, j = (c - 16) % 3;
      const int D2 = 3;
      ACCP(1,  1,   3)
      ACCP(9,  35,  1)
      ACCP(13, 41,  3)
      ACCP(19, 65,  5)
      ACCP(35, 115, 3)
      ACCP(41, 139, 5)
    } else {                        // l2 = 2 : paths 2,6,8,9,12,14
      const int v = (c - 64) / 5, j = (c - 64) % 5;
      const int D2 = 5;
      ACCP(4,  10,  5)
      ACCP(16, 50,  3)
      ACCP(24, 80,  5)
      ACCP(29, 105, 1)
      ACCP(38, 124, 3)
      ACCP(46, 164, 5)
    }
    *(float4*)&pM[c * 12]     = make_float4(acc[0], acc[1], acc[2], acc[3]);
    *(float4*)&pM[c * 12 + 4] = make_float4(acc[4], acc[5], acc[6], acc[7]);
    pM[c * 12 + 8] = acc[8];
  }
  __syncthreads();   // all waves done reading sB8/sB1/pT before U is overlaid

  // ---- stage X2 row-major pad-148 (b128 writes, ~conflict-free: R13) ----
  float* sX2R = U;
  #pragma unroll
  for (int k = 0; k < 9; ++k){
    int q = k * 256 + tid;                       // 0..2303 float4 tasks
    int j = q / 36, c4 = q - j * 36;
    const float4 xv = *(const float4*)(feats + (size_t)sCol[j] * 144 + c4 * 4);
    *(float4*)(sX2R + j * 148 + c4 * 4) = xv;
  }
  __syncthreads();

  // ---- cart: acc[a] = sum_c x2[j][c] * Mq[c][a] ----
  // x via b128 (36 reads); Mq via LDS broadcast (fused2 idiom, same order).
  const float* xrow = sX2R + lane * 148;
  float acc[9];
  #pragma unroll
  for (int a = 0; a < 9; ++a) acc[a] = 0.f;

  #pragma unroll 4
  for (int c4 = 0; c4 < 36; ++c4){
    float4 xv = *(const float4*)(xrow + c4 * 4);
    #pragma unroll
    for (int r = 0; r < 4; ++r){
      int c = c4 * 4 + r;
      float xs = (r == 0) ? xv.x : ((r == 1) ? xv.y : ((r == 2) ? xv.z : xv.w));
      const float4 m0 = *(const float4*)&pM[c * 12];
      const float4 m1 = *(const float4*)&pM[c * 12 + 4];
      const float  m8 = pM[c * 12 + 8];
      acc[0] += xs * m0.x; acc[1] += xs * m0.y; acc[2] += xs * m0.z;
      acc[3] += xs * m0.w; acc[4] += xs * m1.x; acc[5] += xs * m1.y;
      acc[6] += xs * m1.z; acc[7] += xs * m1.w; acc[8] += xs * m8;
    }
  }

  // ---- coalesced store via LDS staging (wave-local region of U) ----
  float* pO = U + 9472 + wave * 576;
  #pragma unroll
  for (int a = 0; a < 9; ++a) pO[lane * 9 + a] = acc[a];
  float* ob = out + (size_t)rw * 576;
  #pragma unroll
  for (int r = 0; r < 3; ++r){
    int idx = lane + r * 64;                     // float4 index 0..143
    if (idx < 144){
      float4 vv = *(const float4*)(pO + idx * 4);
      *(float4*)(ob + idx * 4) = vv;
    }
  }
}

// ---------------------------------------------------------------------------
// sym_tiled: 16x16 cell tile-pairs through LDS; fully coalesced; each element
// read+written exactly once. Block = (config b, tile-pair tp), 256 threads.
// ---------------------------------------------------------------------------
__global__ __launch_bounds__(256) void sym_tiled(float* __restrict__ out){
  __shared__ float sA[16 * 145];
  __shared__ float sB[16 * 145];
  const int tid = threadIdx.x;
  const int b  = blockIdx.x / 10;
  const int tp = blockIdx.x - b * 10;
  const int TI[10] = {0,0,0,0,1,1,1,2,2,3};
  const int TJ[10] = {0,1,2,3,1,2,3,2,3,3};
  const int ti = TI[tp], tj = TJ[tp];
  const bool diag = (ti == tj);
  const size_t cfgBase = (size_t)b * 4096 * 9;

  for (int idx = tid; idx < 2304; idx += 256){
    int r = idx / 144, off = idx - r * 144;
    sA[r * 145 + off] = out[cfgBase + ((size_t)(ti*16 + r) * 64 + tj*16) * 9 + off];
  }
  if (!diag){
    for (int idx = tid; idx < 2304; idx += 256){
      int r = idx / 144, off = idx - r * 144;
      sB[r * 145 + off] = out[cfgBase + ((size_t)(tj*16 + r) * 64 + ti*16) * 9 + off];
    }
  }
  __syncthreads();

  const int di = tid >> 4, dj = tid & 15;
  const float* A = sA;
  const float* B = diag ? sA : sB;
  float oa[9], ob[9];
  #pragma unroll
  for (int a = 0; a < 3; ++a)
    #pragma unroll
    for (int d = 0; d < 3; ++d){
      oa[a*3+d] = 0.5f * (A[di*145 + dj*9 + a*3+d] + B[dj*145 + di*9 + d*3+a]);
      if (!diag)
        ob[a*3+d] = 0.5f * (B[di*145 + dj*9 + a*3+d] + A[dj*145 + di*9 + d*3+a]);
    }
  __syncthreads();

  #pragma unroll
  for (int r9 = 0; r9 < 9; ++r9) sA[di*145 + dj*9 + r9] = oa[r9];
  if (!diag){
    #pragma unroll
    for (int r9 = 0; r9 < 9; ++r9) sB[di*145 + dj*9 + r9] = ob[r9];
  }
  __syncthreads();

  for (int idx = tid; idx < 2304; idx += 256){
    int r = idx / 144, off = idx - r * 144;
    out[cfgBase + ((size_t)(ti*16 + r) * 64 + tj*16) * 9 + off] = sA[r * 145 + off];
  }
  if (!diag){
    for (int idx = tid; idx < 2304; idx += 256){
      int r = idx / 144, off = idx - r * 144;
      out[cfgBase + ((size_t)(tj*16 + r) * 64 + ti*16) * 9 + off] = sB[r * 145 + off];
    }
  }
}

// ---------------------------------------------------------------------------
extern "C" void kernel_launch(void* const* d_in, const int* in_sizes, int n_in,
                              void* d_out, int out_size, void* d_ws, size_t ws_size,
                              hipStream_t stream) {
  const float* feats  = (const float*)d_in[0];   // (4096, 144)
  const int*   layout = (const int*)  d_in[1];   // (E, 2)
  const float* tpw    = (const float*)d_in[2];   // (15, 16, 16)
  float* out = (float*)d_out;
  (void)d_ws; (void)ws_size; (void)n_in; (void)out_size;

  const int E = in_sizes[1] / 2;                 // 262144
  const int R = E / 64;                          // 4096 row-blocks
  const int B = E / 4096;                        // 64 configs

  fused8_kernel<<<R / 4, 256, 0, stream>>>(feats, layout, tpw, out);
  sym_tiled<<<B * 10, 256, 0, stream>>>(out);
}